// Round 7
// baseline (80.333 us; speedup 1.0000x reference)
//
#include <hip/hip_runtime.h>
#include <math.h>

#define N 1024
#define D 128
#define CAP 128
#define MAXNORM 0.996f
#define MINN 1e-15f
#define MAGIC1 0x5FC3A7E1u
#define MAGIC2 0xA03C581Eu

__device__ __forceinline__ float wave_sum(float v) {
#pragma unroll
    for (int o = 32; o > 0; o >>= 1) v += __shfl_xor(v, o, 64);
    return v;
}

__device__ __forceinline__ void wave_sum2(float& a, float& b) {
#pragma unroll
    for (int o = 32; o > 0; o >>= 1) {
        a += __shfl_xor(a, o, 64);
        b += __shfl_xor(b, o, 64);
    }
}

__device__ __forceinline__ float group16_sum(float v) {
#pragma unroll
    for (int o = 8; o > 0; o >>= 1) v += __shfl_xor(v, o, 64);
    return v;
}

__device__ __forceinline__ float artanh_fast(float x) {
    x = fminf(fmaxf(x, -1.0f + 1e-7f), 1.0f - 1e-7f);
    return 0.5f * __logf(__fdividef(1.0f + x, 1.0f - x));
}

// One cooperative kernel: 1024 blocks (1 row each) x 256 threads, all co-resident.
// Phase 1: matvec+bias chain -> h,h2,sL,sR; publish per-row done-flag (release).
// Spin on neighbor flags (acquire), then Phase 2: sparse aggregation + epilogue.
__global__ __launch_bounds__(256, 4) void k_one(
    const float* __restrict__ x, const float* __restrict__ adj,
    const float* __restrict__ Wm, const float* __restrict__ bias,
    const float* __restrict__ attw, const float* __restrict__ attb_p,
    float* __restrict__ h, float* __restrict__ h2a, float* __restrict__ sLa,
    float* __restrict__ sRa, unsigned int* __restrict__ flag1,
    unsigned int* __restrict__ flag2, float* __restrict__ out) {
    __shared__ float smv[D];
    __shared__ int wcnt[4];
    __shared__ int lst[CAP];
    __shared__ float vals[CAP];
    __shared__ float his[D];
    __shared__ float sc_h2, sc_sL;
    __shared__ float accS[16][132];
    __shared__ float sAs[16];

    const int t = threadIdx.x, w = t >> 6, l = t & 63;
    const int g = l >> 4, m = l & 15;
    const int i = blockIdx.x;
    const unsigned long long lt_mask = (1ull << l) - 1ull;

    // issue adj-row segment load early (hides HBM latency under the matvec)
    float4 av = *(const float4*)(adj + (size_t)i * N + (w << 8) + 4 * l);

    // x-row chunks (reused across all 8 matvec passes)
    float4 xa = *(const float4*)(x + (size_t)i * D + 4 * m);
    float4 xb = *(const float4*)(x + (size_t)i * D + 64 + 4 * m);

    float xn2 = group16_sum(xa.x * xa.x + xa.y * xa.y + xa.z * xa.z +
                            xa.w * xa.w + xb.x * xb.x + xb.y * xb.y +
                            xb.z * xb.z + xb.w * xb.w);

    // matvec: wave w covers outputs [32w,32w+32); group g does output 32w+4p+g
#pragma unroll
    for (int p = 0; p < 8; ++p) {
        const int o = (w << 5) + (p << 2) + g;
        float4 wa = *(const float4*)(Wm + (size_t)o * D + 4 * m);
        float4 wb = *(const float4*)(Wm + (size_t)o * D + 64 + 4 * m);
        float s = xa.x * wa.x + xa.y * wa.y + xa.z * wa.z + xa.w * wa.w +
                  xb.x * wb.x + xb.y * wb.y + xb.z * wb.z + xb.w * wb.w;
        s = group16_sum(s);
        if (m == 0) smv[o] = s;
    }

    // ballot compaction bookkeeping
    float ae[4] = {av.x, av.y, av.z, av.w};
    unsigned long long msk[4];
    int cnt = 0;
#pragma unroll
    for (int e = 0; e < 4; ++e) {
        msk[e] = __ballot(ae[e] != 0.0f);
        cnt += __popcll(msk[e]);
    }
    if (l == 0) wcnt[w] = cnt;
    __syncthreads();  // [A] publishes smv and wcnt

    int base = 0;
#pragma unroll
    for (int ww = 0; ww < 4; ++ww)
        if (ww < w) base += wcnt[ww];
    int tot = wcnt[0] + wcnt[1] + wcnt[2] + wcnt[3];
    tot = (tot < CAP) ? tot : CAP;
    {
        int off = base;
#pragma unroll
        for (int e = 0; e < 4; ++e) {
            if (ae[e] != 0.0f) {
                int pos = off + __popcll(msk[e] & lt_mask);
                if (pos < CAP) {
                    lst[pos] = (w << 8) + 4 * l + e;
                    vals[pos] = ae[e];
                }
            }
            off += __popcll(msk[e]);
        }
    }

    // ---- wave 0: bias chain + mobius scalar chain; publish row i
    if (w == 0) {
        float2 bv = *(const float2*)(bias + 2 * l);
        float bn2 = wave_sum(bv.x * bv.x + bv.y * bv.y);
        float bn = fmaxf(sqrtf(bn2), MINN);
        float tb = tanhf(bn);
        float bs = tb / bn;
        float2 hbv = make_float2(bs * bv.x, bs * bv.y);
        float vn = tb;  // |expmap0(bias)| = tanh(|bias|)
        if (vn > MAXNORM) {
            float sc0 = MAXNORM / vn;
            hbv.x *= sc0; hbv.y *= sc0;
            vn = MAXNORM;
        }
        float y2 = vn * vn;

        float2 mv = *(const float2*)(&smv[2 * l]);
        float mxn2 = wave_sum(mv.x * mv.x + mv.y * mv.y);
        float mxn = fmaxf(sqrtf(mxn2), MINN);
        float xn = fmaxf(sqrtf(xn2), MINN);
        float rn = tanhf(mxn / xn * artanh_fast(xn));  // = |mobius_matvec| >= 0
        float sc = rn / mxn;
        float r0 = sc * mv.x, r1 = sc * mv.y;
        float sr = (rn > MAXNORM) ? (MAXNORM / rn) : 1.f;
        r0 *= sr; r1 *= sr;
        float rn_c = rn * sr;
        float x2 = rn_c * rn_c;

        float xy = wave_sum(r0 * hbv.x + r1 * hbv.y);
        float den = fmaxf(1.f + 2.f * xy + x2 * y2, MINN);
        float ca = (1.f + 2.f * xy + y2) / den;
        float cb = (1.f - x2) / den;
        float hp0 = ca * r0 + cb * hbv.x;
        float hp1 = ca * r1 + cb * hbv.y;
        float hn2 = wave_sum(hp0 * hp0 + hp1 * hp1);
        float hn = fmaxf(sqrtf(hn2), MINN);
        float sh = (hn > MAXNORM) ? (MAXNORM / hn) : 1.f;
        hp0 *= sh; hp1 *= sh;
        float h2 = hn2 * sh * sh;

        float hnn = fmaxf(sqrtf(h2), MINN);
        float fac = artanh_fast(hnn) / hnn;
        float dwl = wave_sum(hp0 * attw[2 * l] + hp1 * attw[2 * l + 1]);
        float dwr = wave_sum(hp0 * attw[D + 2 * l] + hp1 * attw[D + 2 * l + 1]);

        *(float2*)(h + (size_t)i * D + 2 * l) = make_float2(hp0, hp1);
        *(float2*)(&his[2 * l]) = make_float2(hp0, hp1);
        if (l == 0) {
            h2a[i] = h2;
            sLa[i] = fac * dwl;
            sRa[i] = fac * dwr;
            sc_h2 = h2;
            sc_sL = fac * dwl;
            // release: prior global stores (this wave) visible before flags
            __hip_atomic_store(&flag1[i], MAGIC1, __ATOMIC_RELEASE,
                               __HIP_MEMORY_SCOPE_AGENT);
            __hip_atomic_store(&flag2[i], MAGIC2, __ATOMIC_RELEASE,
                               __HIP_MEMORY_SCOPE_AGENT);
        }
    }
    __syncthreads();  // [B] lst/vals/his/sc ready; flag[i] published

    // ---- wait for neighbors (each thread covers a subset; publish was above)
    for (int n = t; n < tot; n += 256) {
        const int j = lst[n];
        while (__hip_atomic_load(&flag1[j], __ATOMIC_ACQUIRE,
                                 __HIP_MEMORY_SCOPE_AGENT) != MAGIC1 ||
               __hip_atomic_load(&flag2[j], __ATOMIC_ACQUIRE,
                                 __HIP_MEMORY_SCOPE_AGENT) != MAGIC2) {
            __builtin_amdgcn_s_sleep(1);
        }
    }
    __syncthreads();  // [C] all neighbor rows visible

    // ---- phase 2: 16 groups of 16 lanes; group gid takes n = gid, gid+16, ...
    const int gid = t >> 4;
    const float h2_i = sc_h2;
    const float sL_i = sc_sL;
    const float attb = attb_p[0];
    const float B = 1.f - h2_i;
    const float cA = fmaxf(B, MINN);

    float4 hi0 = *(const float4*)(&his[8 * m]);
    float4 hi1 = *(const float4*)(&his[8 * m + 4]);

    float4 a0 = make_float4(0.f, 0.f, 0.f, 0.f);
    float4 a1 = make_float4(0.f, 0.f, 0.f, 0.f);
    float sAcc = 0.f;

    for (int n = gid; n < tot; n += 16) {
        const int j = lst[n];
        const float aval = vals[n];
        float4 hj0 = *(const float4*)(h + (size_t)j * D + 8 * m);
        float4 hj1 = *(const float4*)(h + (size_t)j * D + 8 * m + 4);
        float d = hi0.x * hj0.x + hi0.y * hj0.y + hi0.z * hj0.z +
                  hi0.w * hj0.w + hi1.x * hj1.x + hi1.y * hj1.y +
                  hi1.z * hj1.z + hi1.w * hj1.w;
        float dot = group16_sum(d);
        float h2_j = h2a[j];
        float sR_j = sRa[j];
        float den = fmaxf(1.f - 2.f * dot + h2_i * h2_j, MINN);
        float p = __fdividef(-(1.f - 2.f * dot + h2_j), den);
        float q = __fdividef(B, den);
        float n2 = p * p * h2_i + 2.f * p * q * dot + q * q * h2_j;
        float nrm = fmaxf(sqrtf(fmaxf(n2, 0.f)), MINN);
        float coefc = cA * __fdividef(artanh_fast(nrm), nrm);
        float sig = __fdividef(1.f, 1.f + __expf(-(sL_i + sR_j + attb)));
        float wgt = aval * sig;
        sAcc += wgt * coefc * p;
        float wb = wgt * coefc * q;
        a0.x += wb * hj0.x; a0.y += wb * hj0.y;
        a0.z += wb * hj0.z; a0.w += wb * hj0.w;
        a1.x += wb * hj1.x; a1.y += wb * hj1.y;
        a1.z += wb * hj1.z; a1.w += wb * hj1.w;
    }

    *(float4*)(&accS[gid][8 * m]) = a0;
    *(float4*)(&accS[gid][8 * m + 4]) = a1;
    if (m == 0) sAs[gid] = sAcc;
    __syncthreads();  // [D]

    if (w != 0) return;

    // ---- wave 0 epilogue: lane l owns dims (2l, 2l+1)
    float b0 = 0.f, b1 = 0.f, sA = 0.f;
#pragma unroll
    for (int g2 = 0; g2 < 16; ++g2) {
        b0 += accS[g2][2 * l];
        b1 += accS[g2][2 * l + 1];
        sA += sAs[g2];
    }

    float2 hi = *(const float2*)(&his[2 * l]);
    float u0 = sA * hi.x + b0, u1 = sA * hi.y + b1;

    float u2 = u0 * u0 + u1 * u1;
    float hiu = hi.x * u0 + hi.y * u1;
    wave_sum2(u2, hiu);
    float un = fmaxf(sqrtf(u2), MINN);
    float lam = 2.f / cA;
    float th = tanhf(0.5f * lam * un);
    float r = th / un;
    float s0 = r * u0, s1 = r * u1;
    float y2 = th * th;
    float xy = r * hiu;
    float den2 = fmaxf(1.f + 2.f * xy + h2_i * y2, MINN);
    float c1 = (1.f + 2.f * xy + y2) / den2;
    float c2 = (1.f - h2_i) / den2;
    float hp0 = c1 * hi.x + c2 * s0;
    float hp1 = c1 * hi.y + c2 * s1;
    float hn2 = wave_sum(hp0 * hp0 + hp1 * hp1);
    float hn = fmaxf(sqrtf(hn2), MINN);
    float scl = (hn > MAXNORM) ? (MAXNORM / hn) : 1.f;
    hp0 *= scl; hp1 *= scl;
    float n3 = fminf(fmaxf(hn, MINN), MAXNORM);
    float fac = tanhf(n3) / n3;
    float o0 = fac * hp0, o1 = fac * hp1;
    float onrm = tanhf(n3);
    if (onrm > MAXNORM) {
        float ss = MAXNORM / onrm;
        o0 *= ss; o1 *= ss;
    }
    *(float2*)(out + (size_t)i * D + 2 * l) = make_float2(o0, o1);
}

extern "C" void kernel_launch(void* const* d_in, const int* in_sizes, int n_in,
                              void* d_out, int out_size, void* d_ws, size_t ws_size,
                              hipStream_t stream) {
    const float* x = (const float*)d_in[0];
    const float* adj = (const float*)d_in[1];
    const float* Wm = (const float*)d_in[2];
    const float* bias = (const float*)d_in[3];
    const float* attw = (const float*)d_in[4];
    const float* attb = (const float*)d_in[5];
    float* out = (float*)d_out;

    float* ws = (float*)d_ws;
    float* h = ws;                            // N*D
    float* h2a = h + (size_t)N * D;           // N
    float* sL = h2a + N;                      // N
    float* sR = sL + N;                       // N
    unsigned int* flag1 = (unsigned int*)(sR + N);  // N
    unsigned int* flag2 = flag1 + N;                // N

    void* args[] = {(void*)&x,    (void*)&adj,  (void*)&Wm,    (void*)&bias,
                    (void*)&attw, (void*)&attb, (void*)&h,     (void*)&h2a,
                    (void*)&sL,   (void*)&sR,   (void*)&flag1, (void*)&flag2,
                    (void*)&out};
    hipLaunchCooperativeKernel((const void*)k_one, dim3(N), dim3(256), args, 0,
                               stream);
}

// Round 8
// 55.832 us; speedup vs baseline: 1.4388x; 1.4388x over previous
//
#include <hip/hip_runtime.h>
#include <math.h>

#define N 1024
#define D 128
#define CAP 128
#define MAXNORM 0.996f
#define MINN 1e-15f
#define MAGIC 0x5FC3A7E1u

typedef unsigned long long u64;
typedef unsigned int u32;

__device__ __forceinline__ float wave_sum(float v) {
#pragma unroll
    for (int o = 32; o > 0; o >>= 1) v += __shfl_xor(v, o, 64);
    return v;
}

__device__ __forceinline__ void wave_sum2(float& a, float& b) {
#pragma unroll
    for (int o = 32; o > 0; o >>= 1) {
        a += __shfl_xor(a, o, 64);
        b += __shfl_xor(b, o, 64);
    }
}

__device__ __forceinline__ float group16_sum(float v) {
#pragma unroll
    for (int o = 8; o > 0; o >>= 1) v += __shfl_xor(v, o, 64);
    return v;
}

__device__ __forceinline__ float artanh_fast(float x) {
    x = fminf(fmaxf(x, -1.0f + 1e-7f), 1.0f - 1e-7f);
    return 0.5f * __logf(__fdividef(1.0f + x, 1.0f - x));
}

// relaxed agent-scope ops: performed at the coherence point (sc1), NO cache
// invalidate/writeback side effects (the R7 killer).
__device__ __forceinline__ u64 ldc64(const u64* p) {
    return __hip_atomic_load(p, __ATOMIC_RELAXED, __HIP_MEMORY_SCOPE_AGENT);
}
__device__ __forceinline__ u64 pack2(float a, float b) {
    return (u64)__float_as_uint(a) | ((u64)__float_as_uint(b) << 32);
}
__device__ __forceinline__ float2 unpack2(u64 v) {
    return make_float2(__uint_as_float((u32)v),
                       __uint_as_float((u32)(v >> 32)));
}

// Single cooperative dispatch: 1024 blocks (1 row each) x 256 threads, all
// co-resident (launch_bounds 256,4 -> 4 blocks/CU x 256 CUs = 1024).
// Phase 1 -> publish flag[i] (one RELEASE store per block).
// Spin on neighbor flags with RELAXED loads, then Phase 2.
__global__ __launch_bounds__(256, 4) void k_one(
    const float* __restrict__ x, const float* __restrict__ adj,
    const float* __restrict__ Wm, const float* __restrict__ bias,
    const float* __restrict__ attw, const float* __restrict__ attb_p,
    u64* __restrict__ h64, u64* __restrict__ hs, u32* __restrict__ flag,
    float* __restrict__ out) {
    __shared__ float smv[D];
    __shared__ int wcnt[4];
    __shared__ int lst[CAP];
    __shared__ float vals[CAP];
    __shared__ float his[D];
    __shared__ float sc_h2, sc_sL;
    __shared__ float accS[16][132];
    __shared__ float sAs[16];

    const int t = threadIdx.x, w = t >> 6, l = t & 63;
    const int g = l >> 4, m = l & 15;
    const int i = blockIdx.x;
    const unsigned long long lt_mask = (1ull << l) - 1ull;

    // issue adj-row segment load early (hides HBM latency under the matvec)
    float4 av = *(const float4*)(adj + (size_t)i * N + (w << 8) + 4 * l);

    // x-row chunks (reused across all 8 matvec passes)
    float4 xa = *(const float4*)(x + (size_t)i * D + 4 * m);
    float4 xb = *(const float4*)(x + (size_t)i * D + 64 + 4 * m);

    float xn2 = group16_sum(xa.x * xa.x + xa.y * xa.y + xa.z * xa.z +
                            xa.w * xa.w + xb.x * xb.x + xb.y * xb.y +
                            xb.z * xb.z + xb.w * xb.w);

    // matvec: wave w covers outputs [32w,32w+32); group g does output 32w+4p+g
#pragma unroll
    for (int p = 0; p < 8; ++p) {
        const int o = (w << 5) + (p << 2) + g;
        float4 wa = *(const float4*)(Wm + (size_t)o * D + 4 * m);
        float4 wb = *(const float4*)(Wm + (size_t)o * D + 64 + 4 * m);
        float s = xa.x * wa.x + xa.y * wa.y + xa.z * wa.z + xa.w * wa.w +
                  xb.x * wb.x + xb.y * wb.y + xb.z * wb.z + xb.w * wb.w;
        s = group16_sum(s);
        if (m == 0) smv[o] = s;
    }

    // ballot compaction bookkeeping
    float ae[4] = {av.x, av.y, av.z, av.w};
    unsigned long long msk[4];
    int cnt = 0;
#pragma unroll
    for (int e = 0; e < 4; ++e) {
        msk[e] = __ballot(ae[e] != 0.0f);
        cnt += __popcll(msk[e]);
    }
    if (l == 0) wcnt[w] = cnt;
    __syncthreads();  // [A] publishes smv and wcnt

    int base = 0;
#pragma unroll
    for (int ww = 0; ww < 4; ++ww)
        if (ww < w) base += wcnt[ww];
    int tot = wcnt[0] + wcnt[1] + wcnt[2] + wcnt[3];
    tot = (tot < CAP) ? tot : CAP;
    {
        int off = base;
#pragma unroll
        for (int e = 0; e < 4; ++e) {
            if (ae[e] != 0.0f) {
                int pos = off + __popcll(msk[e] & lt_mask);
                if (pos < CAP) {
                    lst[pos] = (w << 8) + 4 * l + e;
                    vals[pos] = ae[e];
                }
            }
            off += __popcll(msk[e]);
        }
    }

    // ---- wave 0: bias chain + mobius scalar chain; then publish row i
    if (w == 0) {
        float2 bv = *(const float2*)(bias + 2 * l);
        float bn2 = wave_sum(bv.x * bv.x + bv.y * bv.y);
        float bn = fmaxf(sqrtf(bn2), MINN);
        float tb = tanhf(bn);
        float bs = tb / bn;
        float2 hbv = make_float2(bs * bv.x, bs * bv.y);
        float vn = tb;  // |expmap0(bias)| = tanh(|bias|)
        if (vn > MAXNORM) {
            float sc0 = MAXNORM / vn;
            hbv.x *= sc0; hbv.y *= sc0;
            vn = MAXNORM;
        }
        float y2 = vn * vn;

        float2 mv = *(const float2*)(&smv[2 * l]);
        float mxn2 = wave_sum(mv.x * mv.x + mv.y * mv.y);
        float mxn = fmaxf(sqrtf(mxn2), MINN);
        float xn = fmaxf(sqrtf(xn2), MINN);
        float rn = tanhf(mxn / xn * artanh_fast(xn));  // = |mobius_matvec| >= 0
        float sc = rn / mxn;
        float r0 = sc * mv.x, r1 = sc * mv.y;
        float sr = (rn > MAXNORM) ? (MAXNORM / rn) : 1.f;
        r0 *= sr; r1 *= sr;
        float rn_c = rn * sr;
        float x2 = rn_c * rn_c;

        float xy = wave_sum(r0 * hbv.x + r1 * hbv.y);
        float den = fmaxf(1.f + 2.f * xy + x2 * y2, MINN);
        float ca = (1.f + 2.f * xy + y2) / den;
        float cb = (1.f - x2) / den;
        float hp0 = ca * r0 + cb * hbv.x;
        float hp1 = ca * r1 + cb * hbv.y;
        float hn2 = wave_sum(hp0 * hp0 + hp1 * hp1);
        float hn = fmaxf(sqrtf(hn2), MINN);
        float sh = (hn > MAXNORM) ? (MAXNORM / hn) : 1.f;
        hp0 *= sh; hp1 *= sh;
        float h2 = hn2 * sh * sh;

        float hnn = fmaxf(sqrtf(h2), MINN);
        float fac = artanh_fast(hnn) / hnn;
        float dwl = wave_sum(hp0 * attw[2 * l] + hp1 * attw[2 * l + 1]);
        float dwr = wave_sum(hp0 * attw[D + 2 * l] + hp1 * attw[D + 2 * l + 1]);

        // normal stores (stay in local L2; the RELEASE below flushes them)
        h64[(size_t)i * 64 + l] = pack2(hp0, hp1);
        *(float2*)(&his[2 * l]) = make_float2(hp0, hp1);
        if (l == 0) {
            hs[i] = pack2(h2, fac * dwr);  // (h2_j, sR_j) packed
            sc_h2 = h2;
            sc_sL = fac * dwl;
        }
        // ONE release per block: wbl2 flushes the ~600 dirty bytes above,
        // then the flag store is performed at the coherence point.
        if (l == 0)
            __hip_atomic_store(&flag[i], MAGIC, __ATOMIC_RELEASE,
                               __HIP_MEMORY_SCOPE_AGENT);
    }
    __syncthreads();  // [B] lst/vals/his/sc ready; flag[i] published

    // ---- spin on neighbor flags: wave 0 only, RELAXED loads (no inv)
    if (w == 0) {
        for (int n = l; n < tot; n += 64) {
            const int j = lst[n];
            while (__hip_atomic_load(&flag[j], __ATOMIC_RELAXED,
                                     __HIP_MEMORY_SCOPE_AGENT) != MAGIC) {
                __builtin_amdgcn_s_sleep(1);
            }
        }
    }
    __syncthreads();  // [C] all neighbor rows reached the coherence point

    // ---- phase 2: 16 groups of 16 lanes; group gid takes n = gid, gid+16, ...
    const int gid = t >> 4;
    const float h2_i = sc_h2;
    const float sL_i = sc_sL;
    const float attb = attb_p[0];
    const float B = 1.f - h2_i;
    const float cA = fmaxf(B, MINN);

    float4 hi0 = *(const float4*)(&his[8 * m]);
    float4 hi1 = *(const float4*)(&his[8 * m + 4]);

    float4 a0 = make_float4(0.f, 0.f, 0.f, 0.f);
    float4 a1 = make_float4(0.f, 0.f, 0.f, 0.f);
    float sAcc = 0.f;

    for (int n = gid; n < tot; n += 16) {
        const int j = lst[n];
        const float aval = vals[n];
        // lane m owns dims [8m, 8m+8) = u64 slots 4m..4m+3 of row j
        u64 v0 = ldc64(&h64[(size_t)j * 64 + 4 * m]);
        u64 v1 = ldc64(&h64[(size_t)j * 64 + 4 * m + 1]);
        u64 v2 = ldc64(&h64[(size_t)j * 64 + 4 * m + 2]);
        u64 v3 = ldc64(&h64[(size_t)j * 64 + 4 * m + 3]);
        float2 p0 = unpack2(v0), p1 = unpack2(v1), p2 = unpack2(v2),
               p3 = unpack2(v3);
        float2 q = unpack2(ldc64(&hs[j]));
        float h2_j = q.x, sR_j = q.y;

        float d = hi0.x * p0.x + hi0.y * p0.y + hi0.z * p1.x + hi0.w * p1.y +
                  hi1.x * p2.x + hi1.y * p2.y + hi1.z * p3.x + hi1.w * p3.y;
        float dot = group16_sum(d);
        float den = fmaxf(1.f - 2.f * dot + h2_i * h2_j, MINN);
        float p = __fdividef(-(1.f - 2.f * dot + h2_j), den);
        float qq = __fdividef(B, den);
        float n2 = p * p * h2_i + 2.f * p * qq * dot + qq * qq * h2_j;
        float nrm = fmaxf(sqrtf(fmaxf(n2, 0.f)), MINN);
        float coefc = cA * __fdividef(artanh_fast(nrm), nrm);
        float sig = __fdividef(1.f, 1.f + __expf(-(sL_i + sR_j + attb)));
        float wgt = aval * sig;
        sAcc += wgt * coefc * p;
        float wb = wgt * coefc * qq;
        a0.x += wb * p0.x; a0.y += wb * p0.y;
        a0.z += wb * p1.x; a0.w += wb * p1.y;
        a1.x += wb * p2.x; a1.y += wb * p2.y;
        a1.z += wb * p3.x; a1.w += wb * p3.y;
    }

    *(float4*)(&accS[gid][8 * m]) = a0;
    *(float4*)(&accS[gid][8 * m + 4]) = a1;
    if (m == 0) sAs[gid] = sAcc;
    __syncthreads();  // [D]

    if (w != 0) return;

    // ---- wave 0 epilogue: lane l owns dims (2l, 2l+1)
    float b0 = 0.f, b1 = 0.f, sA = 0.f;
#pragma unroll
    for (int g2 = 0; g2 < 16; ++g2) {
        b0 += accS[g2][2 * l];
        b1 += accS[g2][2 * l + 1];
        sA += sAs[g2];
    }

    float2 hi = *(const float2*)(&his[2 * l]);
    float u0 = sA * hi.x + b0, u1 = sA * hi.y + b1;

    float u2 = u0 * u0 + u1 * u1;
    float hiu = hi.x * u0 + hi.y * u1;
    wave_sum2(u2, hiu);
    float un = fmaxf(sqrtf(u2), MINN);
    float lam = 2.f / cA;
    float th = tanhf(0.5f * lam * un);
    float r = th / un;
    float s0 = r * u0, s1 = r * u1;
    float y2 = th * th;
    float xy = r * hiu;
    float den2 = fmaxf(1.f + 2.f * xy + h2_i * y2, MINN);
    float c1 = (1.f + 2.f * xy + y2) / den2;
    float c2 = (1.f - h2_i) / den2;
    float hp0 = c1 * hi.x + c2 * s0;
    float hp1 = c1 * hi.y + c2 * s1;
    float hn2 = wave_sum(hp0 * hp0 + hp1 * hp1);
    float hn = fmaxf(sqrtf(hn2), MINN);
    float scl = (hn > MAXNORM) ? (MAXNORM / hn) : 1.f;
    hp0 *= scl; hp1 *= scl;
    float n3 = fminf(fmaxf(hn, MINN), MAXNORM);
    float fac = tanhf(n3) / n3;
    float o0 = fac * hp0, o1 = fac * hp1;
    float onrm = tanhf(n3);
    if (onrm > MAXNORM) {
        float ss = MAXNORM / onrm;
        o0 *= ss; o1 *= ss;
    }
    *(float2*)(out + (size_t)i * D + 2 * l) = make_float2(o0, o1);
}

extern "C" void kernel_launch(void* const* d_in, const int* in_sizes, int n_in,
                              void* d_out, int out_size, void* d_ws, size_t ws_size,
                              hipStream_t stream) {
    const float* x = (const float*)d_in[0];
    const float* adj = (const float*)d_in[1];
    const float* Wm = (const float*)d_in[2];
    const float* bias = (const float*)d_in[3];
    const float* attw = (const float*)d_in[4];
    const float* attb = (const float*)d_in[5];
    float* out = (float*)d_out;

    u64* h64 = (u64*)d_ws;                 // N*64 u64 (h rows, packed float2)
    u64* hs = h64 + (size_t)N * 64;        // N u64 (h2, sR)
    u32* flag = (u32*)(hs + N);            // N u32

    void* args[] = {(void*)&x,    (void*)&adj,  (void*)&Wm,  (void*)&bias,
                    (void*)&attw, (void*)&attb, (void*)&h64, (void*)&hs,
                    (void*)&flag, (void*)&out};
    hipLaunchCooperativeKernel((const void*)k_one, dim3(N), dim3(256), args, 0,
                               stream);
}

// Round 9
// 21.227 us; speedup vs baseline: 3.7844x; 2.6302x over previous
//
#include <hip/hip_runtime.h>
#include <math.h>

#define N 1024
#define D 128
#define CAP 128
#define MAXNORM 0.996f
#define MINN 1e-15f
#define MAGIC 0x5FC3A7E1u

typedef unsigned long long u64;
typedef unsigned int u32;

__device__ __forceinline__ float wave_sum(float v) {
#pragma unroll
    for (int o = 32; o > 0; o >>= 1) v += __shfl_xor(v, o, 64);
    return v;
}

__device__ __forceinline__ void wave_sum2(float& a, float& b) {
#pragma unroll
    for (int o = 32; o > 0; o >>= 1) {
        a += __shfl_xor(a, o, 64);
        b += __shfl_xor(b, o, 64);
    }
}

__device__ __forceinline__ float group16_sum(float v) {
#pragma unroll
    for (int o = 8; o > 0; o >>= 1) v += __shfl_xor(v, o, 64);
    return v;
}

__device__ __forceinline__ float artanh_fast(float x) {
    x = fminf(fmaxf(x, -1.0f + 1e-7f), 1.0f - 1e-7f);
    return 0.5f * __logf(__fdividef(1.0f + x, 1.0f - x));
}

// Relaxed agent-scope ops: read/write at the coherence point (sc1).
// NO buffer_inv / buffer_wbl2 side effects (the R7/R8 killer).
__device__ __forceinline__ u64 ldc64(const u64* p) {
    return __hip_atomic_load(p, __ATOMIC_RELAXED, __HIP_MEMORY_SCOPE_AGENT);
}
__device__ __forceinline__ u32 ldc32(const u32* p) {
    return __hip_atomic_load(p, __ATOMIC_RELAXED, __HIP_MEMORY_SCOPE_AGENT);
}
__device__ __forceinline__ void stc64(u64* p, u64 v) {
    __hip_atomic_store(p, v, __ATOMIC_RELAXED, __HIP_MEMORY_SCOPE_AGENT);
}
__device__ __forceinline__ void stc32(u32* p, u32 v) {
    __hip_atomic_store(p, v, __ATOMIC_RELAXED, __HIP_MEMORY_SCOPE_AGENT);
}
__device__ __forceinline__ u64 pack2(float a, float b) {
    return (u64)__float_as_uint(a) | ((u64)__float_as_uint(b) << 32);
}
__device__ __forceinline__ float2 unpack2(u64 v) {
    return make_float2(__uint_as_float((u32)v),
                       __uint_as_float((u32)(v >> 32)));
}

// Single REGULAR dispatch: 1024 blocks (1 row each) x 256 threads.
// All blocks co-resident by capacity (256 thr, ~36 VGPR, ~10.5 KB LDS ->
// >=8 blocks/CU by every resource; grid = 4/CU). Publish-before-spin makes
// the flag protocol deadlock-free under any dispatch order.
__global__ __launch_bounds__(256, 4) void k_one(
    const float* __restrict__ x, const float* __restrict__ adj,
    const float* __restrict__ Wm, const float* __restrict__ bias,
    const float* __restrict__ attw, const float* __restrict__ attb_p,
    u64* __restrict__ h64, u64* __restrict__ hs, u32* __restrict__ flag,
    float* __restrict__ out) {
    __shared__ float smv[D];
    __shared__ int wcnt[4];
    __shared__ int lst[CAP];
    __shared__ float vals[CAP];
    __shared__ float his[D];
    __shared__ float sc_h2, sc_sL;
    __shared__ float accS[16][132];
    __shared__ float sAs[16];

    const int t = threadIdx.x, w = t >> 6, l = t & 63;
    const int g = l >> 4, m = l & 15;
    const int i = blockIdx.x;
    const unsigned long long lt_mask = (1ull << l) - 1ull;

    // issue adj-row segment load early (hides HBM latency under the matvec)
    float4 av = *(const float4*)(adj + (size_t)i * N + (w << 8) + 4 * l);

    // x-row chunks (reused across all 8 matvec passes)
    float4 xa = *(const float4*)(x + (size_t)i * D + 4 * m);
    float4 xb = *(const float4*)(x + (size_t)i * D + 64 + 4 * m);

    float xn2 = group16_sum(xa.x * xa.x + xa.y * xa.y + xa.z * xa.z +
                            xa.w * xa.w + xb.x * xb.x + xb.y * xb.y +
                            xb.z * xb.z + xb.w * xb.w);

    // matvec: wave w covers outputs [32w,32w+32); group g does output 32w+4p+g
#pragma unroll
    for (int p = 0; p < 8; ++p) {
        const int o = (w << 5) + (p << 2) + g;
        float4 wa = *(const float4*)(Wm + (size_t)o * D + 4 * m);
        float4 wb = *(const float4*)(Wm + (size_t)o * D + 64 + 4 * m);
        float s = xa.x * wa.x + xa.y * wa.y + xa.z * wa.z + xa.w * wa.w +
                  xb.x * wb.x + xb.y * wb.y + xb.z * wb.z + xb.w * wb.w;
        s = group16_sum(s);
        if (m == 0) smv[o] = s;
    }

    // ballot compaction bookkeeping
    float ae[4] = {av.x, av.y, av.z, av.w};
    unsigned long long msk[4];
    int cnt = 0;
#pragma unroll
    for (int e = 0; e < 4; ++e) {
        msk[e] = __ballot(ae[e] != 0.0f);
        cnt += __popcll(msk[e]);
    }
    if (l == 0) wcnt[w] = cnt;
    __syncthreads();  // [A] publishes smv and wcnt

    int base = 0;
#pragma unroll
    for (int ww = 0; ww < 4; ++ww)
        if (ww < w) base += wcnt[ww];
    int tot = wcnt[0] + wcnt[1] + wcnt[2] + wcnt[3];
    tot = (tot < CAP) ? tot : CAP;
    {
        int off = base;
#pragma unroll
        for (int e = 0; e < 4; ++e) {
            if (ae[e] != 0.0f) {
                int pos = off + __popcll(msk[e] & lt_mask);
                if (pos < CAP) {
                    lst[pos] = (w << 8) + 4 * l + e;
                    vals[pos] = ae[e];
                }
            }
            off += __popcll(msk[e]);
        }
    }

    // ---- wave 0: bias chain + mobius scalar chain; then publish row i
    if (w == 0) {
        float2 bv = *(const float2*)(bias + 2 * l);
        float bn2 = wave_sum(bv.x * bv.x + bv.y * bv.y);
        float bn = fmaxf(sqrtf(bn2), MINN);
        float tb = tanhf(bn);
        float bs = tb / bn;
        float2 hbv = make_float2(bs * bv.x, bs * bv.y);
        float vn = tb;  // |expmap0(bias)| = tanh(|bias|)
        if (vn > MAXNORM) {
            float sc0 = MAXNORM / vn;
            hbv.x *= sc0; hbv.y *= sc0;
            vn = MAXNORM;
        }
        float y2 = vn * vn;

        float2 mv = *(const float2*)(&smv[2 * l]);
        float mxn2 = wave_sum(mv.x * mv.x + mv.y * mv.y);
        float mxn = fmaxf(sqrtf(mxn2), MINN);
        float xn = fmaxf(sqrtf(xn2), MINN);
        float rn = tanhf(mxn / xn * artanh_fast(xn));  // = |mobius_matvec| >= 0
        float sc = rn / mxn;
        float r0 = sc * mv.x, r1 = sc * mv.y;
        float sr = (rn > MAXNORM) ? (MAXNORM / rn) : 1.f;
        r0 *= sr; r1 *= sr;
        float rn_c = rn * sr;
        float x2 = rn_c * rn_c;

        float xy = wave_sum(r0 * hbv.x + r1 * hbv.y);
        float den = fmaxf(1.f + 2.f * xy + x2 * y2, MINN);
        float ca = (1.f + 2.f * xy + y2) / den;
        float cb = (1.f - x2) / den;
        float hp0 = ca * r0 + cb * hbv.x;
        float hp1 = ca * r1 + cb * hbv.y;
        float hn2 = wave_sum(hp0 * hp0 + hp1 * hp1);
        float hn = fmaxf(sqrtf(hn2), MINN);
        float sh = (hn > MAXNORM) ? (MAXNORM / hn) : 1.f;
        hp0 *= sh; hp1 *= sh;
        float h2 = hn2 * sh * sh;

        float hnn = fmaxf(sqrtf(h2), MINN);
        float fac = artanh_fast(hnn) / hnn;
        float dwl = wave_sum(hp0 * attw[2 * l] + hp1 * attw[2 * l + 1]);
        float dwr = wave_sum(hp0 * attw[D + 2 * l] + hp1 * attw[D + 2 * l + 1]);

        // sc1 stores: data goes to the coherence point directly (no dirty L2)
        stc64(&h64[(size_t)i * 64 + l], pack2(hp0, hp1));
        *(float2*)(&his[2 * l]) = make_float2(hp0, hp1);
        if (l == 0) {
            stc64(&hs[i], pack2(h2, fac * dwr));  // (h2_j, sR_j) packed
            sc_h2 = h2;
            sc_sL = fac * dwl;
        }
        // order: all data stores complete, THEN the flag store
        asm volatile("s_waitcnt vmcnt(0)" ::: "memory");
        if (l == 0) stc32(&flag[i], MAGIC);
    }
    __syncthreads();  // [B] lst/vals/his/sc ready; flag[i] published

    // ---- spin on neighbor flags: wave 0 only, relaxed loads (no cache ops)
    if (w == 0) {
        for (int n = l; n < tot; n += 64) {
            const int j = lst[n];
            while (ldc32(&flag[j]) != MAGIC) {
                __builtin_amdgcn_s_sleep(1);
            }
        }
    }
    __syncthreads();  // [C] all neighbor rows visible at the coherence point

    // ---- phase 2: 16 groups of 16 lanes; group gid takes n = gid, gid+16, ...
    const int gid = t >> 4;
    const float h2_i = sc_h2;
    const float sL_i = sc_sL;
    const float attb = attb_p[0];
    const float B = 1.f - h2_i;
    const float cA = fmaxf(B, MINN);

    float4 hi0 = *(const float4*)(&his[8 * m]);
    float4 hi1 = *(const float4*)(&his[8 * m + 4]);

    float4 a0 = make_float4(0.f, 0.f, 0.f, 0.f);
    float4 a1 = make_float4(0.f, 0.f, 0.f, 0.f);
    float sAcc = 0.f;

    for (int n = gid; n < tot; n += 16) {
        const int j = lst[n];
        const float aval = vals[n];
        // lane m owns dims [8m, 8m+8) = u64 slots 4m..4m+3 of row j
        u64 v0 = ldc64(&h64[(size_t)j * 64 + 4 * m]);
        u64 v1 = ldc64(&h64[(size_t)j * 64 + 4 * m + 1]);
        u64 v2 = ldc64(&h64[(size_t)j * 64 + 4 * m + 2]);
        u64 v3 = ldc64(&h64[(size_t)j * 64 + 4 * m + 3]);
        float2 p0 = unpack2(v0), p1 = unpack2(v1), p2 = unpack2(v2),
               p3 = unpack2(v3);
        float2 q = unpack2(ldc64(&hs[j]));
        float h2_j = q.x, sR_j = q.y;

        float d = hi0.x * p0.x + hi0.y * p0.y + hi0.z * p1.x + hi0.w * p1.y +
                  hi1.x * p2.x + hi1.y * p2.y + hi1.z * p3.x + hi1.w * p3.y;
        float dot = group16_sum(d);
        float den = fmaxf(1.f - 2.f * dot + h2_i * h2_j, MINN);
        float p = __fdividef(-(1.f - 2.f * dot + h2_j), den);
        float qq = __fdividef(B, den);
        float n2 = p * p * h2_i + 2.f * p * qq * dot + qq * qq * h2_j;
        float nrm = fmaxf(sqrtf(fmaxf(n2, 0.f)), MINN);
        float coefc = cA * __fdividef(artanh_fast(nrm), nrm);
        float sig = __fdividef(1.f, 1.f + __expf(-(sL_i + sR_j + attb)));
        float wgt = aval * sig;
        sAcc += wgt * coefc * p;
        float wb = wgt * coefc * qq;
        a0.x += wb * p0.x; a0.y += wb * p0.y;
        a0.z += wb * p1.x; a0.w += wb * p1.y;
        a1.x += wb * p2.x; a1.y += wb * p2.y;
        a1.z += wb * p3.x; a1.w += wb * p3.y;
    }

    *(float4*)(&accS[gid][8 * m]) = a0;
    *(float4*)(&accS[gid][8 * m + 4]) = a1;
    if (m == 0) sAs[gid] = sAcc;
    __syncthreads();  // [D]

    if (w != 0) return;

    // ---- wave 0 epilogue: lane l owns dims (2l, 2l+1)
    float b0 = 0.f, b1 = 0.f, sA = 0.f;
#pragma unroll
    for (int g2 = 0; g2 < 16; ++g2) {
        b0 += accS[g2][2 * l];
        b1 += accS[g2][2 * l + 1];
        sA += sAs[g2];
    }

    float2 hi = *(const float2*)(&his[2 * l]);
    float u0 = sA * hi.x + b0, u1 = sA * hi.y + b1;

    float u2 = u0 * u0 + u1 * u1;
    float hiu = hi.x * u0 + hi.y * u1;
    wave_sum2(u2, hiu);
    float un = fmaxf(sqrtf(u2), MINN);
    float lam = 2.f / cA;
    float th = tanhf(0.5f * lam * un);
    float r = th / un;
    float s0 = r * u0, s1 = r * u1;
    float y2 = th * th;
    float xy = r * hiu;
    float den2 = fmaxf(1.f + 2.f * xy + h2_i * y2, MINN);
    float c1 = (1.f + 2.f * xy + y2) / den2;
    float c2 = (1.f - h2_i) / den2;
    float hp0 = c1 * hi.x + c2 * s0;
    float hp1 = c1 * hi.y + c2 * s1;
    float hn2 = wave_sum(hp0 * hp0 + hp1 * hp1);
    float hn = fmaxf(sqrtf(hn2), MINN);
    float scl = (hn > MAXNORM) ? (MAXNORM / hn) : 1.f;
    hp0 *= scl; hp1 *= scl;
    float n3 = fminf(fmaxf(hn, MINN), MAXNORM);
    float fac = tanhf(n3) / n3;
    float o0 = fac * hp0, o1 = fac * hp1;
    float onrm = tanhf(n3);
    if (onrm > MAXNORM) {
        float ss = MAXNORM / onrm;
        o0 *= ss; o1 *= ss;
    }
    *(float2*)(out + (size_t)i * D + 2 * l) = make_float2(o0, o1);
}

extern "C" void kernel_launch(void* const* d_in, const int* in_sizes, int n_in,
                              void* d_out, int out_size, void* d_ws, size_t ws_size,
                              hipStream_t stream) {
    const float* x = (const float*)d_in[0];
    const float* adj = (const float*)d_in[1];
    const float* Wm = (const float*)d_in[2];
    const float* bias = (const float*)d_in[3];
    const float* attw = (const float*)d_in[4];
    const float* attb = (const float*)d_in[5];
    float* out = (float*)d_out;

    u64* h64 = (u64*)d_ws;                 // N*64 u64 (h rows, packed float2)
    u64* hs = h64 + (size_t)N * 64;        // N u64 (h2, sR)
    u32* flag = (u32*)(hs + N);            // N u32

    hipLaunchKernelGGL(k_one, dim3(N), dim3(256), 0, stream, x, adj, Wm, bias,
                       attw, attb, h64, hs, flag, out);
}

// Round 10
// 20.520 us; speedup vs baseline: 3.9150x; 1.0345x over previous
//
#include <hip/hip_runtime.h>
#include <math.h>

#define N 1024
#define D 128
#define CAP 128
#define MAXNORM 0.996f
#define MINN 1e-15f
#define MAGIC 0x5FC3A7E1u

typedef unsigned long long u64;
typedef unsigned int u32;

__device__ __forceinline__ float wave_sum(float v) {
#pragma unroll
    for (int o = 32; o > 0; o >>= 1) v += __shfl_xor(v, o, 64);
    return v;
}

__device__ __forceinline__ void wave_sum2(float& a, float& b) {
#pragma unroll
    for (int o = 32; o > 0; o >>= 1) {
        a += __shfl_xor(a, o, 64);
        b += __shfl_xor(b, o, 64);
    }
}

__device__ __forceinline__ float group16_sum(float v) {
#pragma unroll
    for (int o = 8; o > 0; o >>= 1) v += __shfl_xor(v, o, 64);
    return v;
}

__device__ __forceinline__ float artanh_fast(float x) {
    x = fminf(fmaxf(x, -1.0f + 1e-7f), 1.0f - 1e-7f);
    return 0.5f * __logf(__fdividef(1.0f + x, 1.0f - x));
}

// sc1 (agent-scope relaxed) ops: ONLY for the producer's publish stores and the
// consumer's flag spins. Phase-2 data reads are PLAIN cached loads: no consumer
// L2 can hold a stale h-line (dispatch-boundary flush + reads only post-flag),
// and plain loads coalesce (the R9 atomic-load path did not).
__device__ __forceinline__ u32 ldc32(const u32* p) {
    return __hip_atomic_load(p, __ATOMIC_RELAXED, __HIP_MEMORY_SCOPE_AGENT);
}
__device__ __forceinline__ void stc64(u64* p, u64 v) {
    __hip_atomic_store(p, v, __ATOMIC_RELAXED, __HIP_MEMORY_SCOPE_AGENT);
}
__device__ __forceinline__ void stc32(u32* p, u32 v) {
    __hip_atomic_store(p, v, __ATOMIC_RELAXED, __HIP_MEMORY_SCOPE_AGENT);
}
__device__ __forceinline__ u64 pack2(float a, float b) {
    return (u64)__float_as_uint(a) | ((u64)__float_as_uint(b) << 32);
}

// Single REGULAR dispatch: 1024 blocks (1 row each) x 256 threads, co-resident
// by capacity (4 blocks/CU). Publish-before-spin => deadlock-free.
__global__ __launch_bounds__(256, 4) void k_one(
    const float* __restrict__ x, const float* __restrict__ adj,
    const float* __restrict__ Wm, const float* __restrict__ bias,
    const float* __restrict__ attw, const float* __restrict__ attb_p,
    u64* __restrict__ h64, u64* __restrict__ hs, u32* __restrict__ flag,
    float* __restrict__ out) {
    __shared__ float smv[D];
    __shared__ int wcnt[4];
    __shared__ int lst[CAP];
    __shared__ float vals[CAP];
    __shared__ float his[D];
    __shared__ float sc_h2, sc_sL;
    __shared__ float accS[16][132];
    __shared__ float sAs[16];

    const int t = threadIdx.x, w = t >> 6, l = t & 63;
    const int g = l >> 4, m = l & 15;
    const int i = blockIdx.x;
    const unsigned long long lt_mask = (1ull << l) - 1ull;

    // issue adj-row segment load early (hides HBM latency under the matvec)
    float4 av = *(const float4*)(adj + (size_t)i * N + (w << 8) + 4 * l);

    // x-row chunks (reused across all 8 matvec passes)
    float4 xa = *(const float4*)(x + (size_t)i * D + 4 * m);
    float4 xb = *(const float4*)(x + (size_t)i * D + 64 + 4 * m);

    float xn2 = group16_sum(xa.x * xa.x + xa.y * xa.y + xa.z * xa.z +
                            xa.w * xa.w + xb.x * xb.x + xb.y * xb.y +
                            xb.z * xb.z + xb.w * xb.w);

    // matvec: wave w covers outputs [32w,32w+32); group g does output 32w+4p+g
#pragma unroll
    for (int p = 0; p < 8; ++p) {
        const int o = (w << 5) + (p << 2) + g;
        float4 wa = *(const float4*)(Wm + (size_t)o * D + 4 * m);
        float4 wb = *(const float4*)(Wm + (size_t)o * D + 64 + 4 * m);
        float s = xa.x * wa.x + xa.y * wa.y + xa.z * wa.z + xa.w * wa.w +
                  xb.x * wb.x + xb.y * wb.y + xb.z * wb.z + xb.w * wb.w;
        s = group16_sum(s);
        if (m == 0) smv[o] = s;
    }

    // ballot compaction bookkeeping
    float ae[4] = {av.x, av.y, av.z, av.w};
    unsigned long long msk[4];
    int cnt = 0;
#pragma unroll
    for (int e = 0; e < 4; ++e) {
        msk[e] = __ballot(ae[e] != 0.0f);
        cnt += __popcll(msk[e]);
    }
    if (l == 0) wcnt[w] = cnt;
    __syncthreads();  // [A] publishes smv and wcnt

    int base = 0;
#pragma unroll
    for (int ww = 0; ww < 4; ++ww)
        if (ww < w) base += wcnt[ww];
    int tot = wcnt[0] + wcnt[1] + wcnt[2] + wcnt[3];
    tot = (tot < CAP) ? tot : CAP;
    {
        int off = base;
#pragma unroll
        for (int e = 0; e < 4; ++e) {
            if (ae[e] != 0.0f) {
                int pos = off + __popcll(msk[e] & lt_mask);
                if (pos < CAP) {
                    lst[pos] = (w << 8) + 4 * l + e;
                    vals[pos] = ae[e];
                }
            }
            off += __popcll(msk[e]);
        }
    }

    // ---- wave 0: bias chain + mobius scalar chain; then publish row i
    if (w == 0) {
        float2 bv = *(const float2*)(bias + 2 * l);
        float bn2 = wave_sum(bv.x * bv.x + bv.y * bv.y);
        float bn = fmaxf(sqrtf(bn2), MINN);
        float tb = tanhf(bn);
        float bs = tb / bn;
        float2 hbv = make_float2(bs * bv.x, bs * bv.y);
        float vn = tb;  // |expmap0(bias)| = tanh(|bias|)
        if (vn > MAXNORM) {
            float sc0 = MAXNORM / vn;
            hbv.x *= sc0; hbv.y *= sc0;
            vn = MAXNORM;
        }
        float y2 = vn * vn;

        float2 mv = *(const float2*)(&smv[2 * l]);
        float mxn2 = wave_sum(mv.x * mv.x + mv.y * mv.y);
        float mxn = fmaxf(sqrtf(mxn2), MINN);
        float xn = fmaxf(sqrtf(xn2), MINN);
        float rn = tanhf(mxn / xn * artanh_fast(xn));  // = |mobius_matvec| >= 0
        float sc = rn / mxn;
        float r0 = sc * mv.x, r1 = sc * mv.y;
        float sr = (rn > MAXNORM) ? (MAXNORM / rn) : 1.f;
        r0 *= sr; r1 *= sr;
        float rn_c = rn * sr;
        float x2 = rn_c * rn_c;

        float xy = wave_sum(r0 * hbv.x + r1 * hbv.y);
        float den = fmaxf(1.f + 2.f * xy + x2 * y2, MINN);
        float ca = (1.f + 2.f * xy + y2) / den;
        float cb = (1.f - x2) / den;
        float hp0 = ca * r0 + cb * hbv.x;
        float hp1 = ca * r1 + cb * hbv.y;
        float hn2 = wave_sum(hp0 * hp0 + hp1 * hp1);
        float hn = fmaxf(sqrtf(hn2), MINN);
        float sh = (hn > MAXNORM) ? (MAXNORM / hn) : 1.f;
        hp0 *= sh; hp1 *= sh;
        float h2 = hn2 * sh * sh;

        float hnn = fmaxf(sqrtf(h2), MINN);
        float fac = artanh_fast(hnn) / hnn;
        float dwl = wave_sum(hp0 * attw[2 * l] + hp1 * attw[2 * l + 1]);
        float dwr = wave_sum(hp0 * attw[D + 2 * l] + hp1 * attw[D + 2 * l + 1]);

        // sc1 stores: data lands at the coherence point (past producer L2)
        stc64(&h64[(size_t)i * 64 + l], pack2(hp0, hp1));
        *(float2*)(&his[2 * l]) = make_float2(hp0, hp1);
        if (l == 0) {
            stc64(&hs[i], pack2(h2, fac * dwr));  // (h2_j, sR_j) packed
            sc_h2 = h2;
            sc_sL = fac * dwl;
        }
        // order: all data stores acked at the coherence point, THEN the flag
        asm volatile("s_waitcnt vmcnt(0)" ::: "memory");
        if (l == 0) stc32(&flag[i], MAGIC);
    }
    __syncthreads();  // [B] lst/vals/his/sc ready; flag[i] published

    // ---- spin on neighbor flags: wave 0 only, relaxed loads (no cache ops)
    if (w == 0) {
        for (int n = l; n < tot; n += 64) {
            const int j = lst[n];
            while (ldc32(&flag[j]) != MAGIC) {
                __builtin_amdgcn_s_sleep(1);
            }
        }
    }
    __syncthreads();  // [C] neighbor data is at the coherence point; no local
                      // L2 holds a pre-publish copy (first touch is post-flag)

    // ---- phase 2: 16 groups of 16 lanes; plain coalesced loads
    const int gid = t >> 4;
    const float h2_i = sc_h2;
    const float sL_i = sc_sL;
    const float attb = attb_p[0];
    const float B = 1.f - h2_i;
    const float cA = fmaxf(B, MINN);

    float4 hi0 = *(const float4*)(&his[8 * m]);
    float4 hi1 = *(const float4*)(&his[8 * m + 4]);

    float4 a0 = make_float4(0.f, 0.f, 0.f, 0.f);
    float4 a1 = make_float4(0.f, 0.f, 0.f, 0.f);
    float sAcc = 0.f;

    for (int n = gid; n < tot; n += 16) {
        const int j = lst[n];
        const float aval = vals[n];
        const float* hj = (const float*)(h64 + (size_t)j * 64);
        float4 hj0 = *(const float4*)(hj + 8 * m);
        float4 hj1 = *(const float4*)(hj + 8 * m + 4);
        float2 q = *(const float2*)(&hs[j]);
        float h2_j = q.x, sR_j = q.y;

        float d = hi0.x * hj0.x + hi0.y * hj0.y + hi0.z * hj0.z +
                  hi0.w * hj0.w + hi1.x * hj1.x + hi1.y * hj1.y +
                  hi1.z * hj1.z + hi1.w * hj1.w;
        float dot = group16_sum(d);
        float den = fmaxf(1.f - 2.f * dot + h2_i * h2_j, MINN);
        float p = __fdividef(-(1.f - 2.f * dot + h2_j), den);
        float qq = __fdividef(B, den);
        float n2 = p * p * h2_i + 2.f * p * qq * dot + qq * qq * h2_j;
        float nrm = fmaxf(sqrtf(fmaxf(n2, 0.f)), MINN);
        float coefc = cA * __fdividef(artanh_fast(nrm), nrm);
        float sig = __fdividef(1.f, 1.f + __expf(-(sL_i + sR_j + attb)));
        float wgt = aval * sig;
        sAcc += wgt * coefc * p;
        float wb = wgt * coefc * qq;
        a0.x += wb * hj0.x; a0.y += wb * hj0.y;
        a0.z += wb * hj0.z; a0.w += wb * hj0.w;
        a1.x += wb * hj1.x; a1.y += wb * hj1.y;
        a1.z += wb * hj1.z; a1.w += wb * hj1.w;
    }

    *(float4*)(&accS[gid][8 * m]) = a0;
    *(float4*)(&accS[gid][8 * m + 4]) = a1;
    if (m == 0) sAs[gid] = sAcc;
    __syncthreads();  // [D]

    if (w != 0) return;

    // ---- wave 0 epilogue: lane l owns dims (2l, 2l+1)
    float b0 = 0.f, b1 = 0.f, sA = 0.f;
#pragma unroll
    for (int g2 = 0; g2 < 16; ++g2) {
        b0 += accS[g2][2 * l];
        b1 += accS[g2][2 * l + 1];
        sA += sAs[g2];
    }

    float2 hi = *(const float2*)(&his[2 * l]);
    float u0 = sA * hi.x + b0, u1 = sA * hi.y + b1;

    float u2 = u0 * u0 + u1 * u1;
    float hiu = hi.x * u0 + hi.y * u1;
    wave_sum2(u2, hiu);
    float un = fmaxf(sqrtf(u2), MINN);
    float lam = 2.f / cA;
    float th = tanhf(0.5f * lam * un);
    float r = th / un;
    float s0 = r * u0, s1 = r * u1;
    float y2 = th * th;
    float xy = r * hiu;
    float den2 = fmaxf(1.f + 2.f * xy + h2_i * y2, MINN);
    float c1 = (1.f + 2.f * xy + y2) / den2;
    float c2 = (1.f - h2_i) / den2;
    float hp0 = c1 * hi.x + c2 * s0;
    float hp1 = c1 * hi.y + c2 * s1;
    float hn2 = wave_sum(hp0 * hp0 + hp1 * hp1);
    float hn = fmaxf(sqrtf(hn2), MINN);
    float scl = (hn > MAXNORM) ? (MAXNORM / hn) : 1.f;
    hp0 *= scl; hp1 *= scl;
    float n3 = fminf(fmaxf(hn, MINN), MAXNORM);
    float fac = tanhf(n3) / n3;
    float o0 = fac * hp0, o1 = fac * hp1;
    float onrm = tanhf(n3);
    if (onrm > MAXNORM) {
        float ss = MAXNORM / onrm;
        o0 *= ss; o1 *= ss;
    }
    *(float2*)(out + (size_t)i * D + 2 * l) = make_float2(o0, o1);
}

extern "C" void kernel_launch(void* const* d_in, const int* in_sizes, int n_in,
                              void* d_out, int out_size, void* d_ws, size_t ws_size,
                              hipStream_t stream) {
    const float* x = (const float*)d_in[0];
    const float* adj = (const float*)d_in[1];
    const float* Wm = (const float*)d_in[2];
    const float* bias = (const float*)d_in[3];
    const float* attw = (const float*)d_in[4];
    const float* attb = (const float*)d_in[5];
    float* out = (float*)d_out;

    u64* h64 = (u64*)d_ws;                 // N*64 u64 (h rows, packed float2)
    u64* hs = h64 + (size_t)N * 64;        // N u64 (h2, sR)
    u32* flag = (u32*)(hs + N);            // N u32

    hipLaunchKernelGGL(k_one, dim3(N), dim3(256), 0, stream, x, adj, Wm, bias,
                       attw, attb, h64, hs, flag, out);
}

// Round 11
// 17.429 us; speedup vs baseline: 4.6092x; 1.1773x over previous
//
#include <hip/hip_runtime.h>
#include <math.h>

#define N 1024
#define D 128
#define CAP 96
#define MAXNORM 0.996f
#define MINN 1e-15f

__device__ __forceinline__ float wave_sum(float v) {
#pragma unroll
    for (int o = 32; o > 0; o >>= 1) v += __shfl_xor(v, o, 64);
    return v;
}

__device__ __forceinline__ void wave_sum2(float& a, float& b) {
#pragma unroll
    for (int o = 32; o > 0; o >>= 1) {
        a += __shfl_xor(a, o, 64);
        b += __shfl_xor(b, o, 64);
    }
}

__device__ __forceinline__ void wave_sum3(float& a, float& b, float& c) {
#pragma unroll
    for (int o = 32; o > 0; o >>= 1) {
        a += __shfl_xor(a, o, 64);
        b += __shfl_xor(b, o, 64);
        c += __shfl_xor(c, o, 64);
    }
}

__device__ __forceinline__ float group16_sum(float v) {
#pragma unroll
    for (int o = 8; o > 0; o >>= 1) v += __shfl_xor(v, o, 64);
    return v;
}

__device__ __forceinline__ float group8_sum(float v) {
#pragma unroll
    for (int o = 4; o > 0; o >>= 1) v += __shfl_xor(v, o, 64);
    return v;
}

__device__ __forceinline__ float artanh_fast(float x) {
    x = fminf(fmaxf(x, -1.0f + 1e-7f), 1.0f - 1e-7f);
    return 0.5f * __logf(__fdividef(1.0f + x, 1.0f - x));
}

// ---- kernel A: one block (4 waves) per row i.
// h row, packed (h2, e^-sR), e^-(sL+attb), and adj-row CSR (cnt / packed edges).
__global__ __launch_bounds__(256) void k_rows(
    const float* __restrict__ x, const float* __restrict__ Wm,
    const float* __restrict__ bias, const float* __restrict__ attw,
    const float* __restrict__ attb_p, const float* __restrict__ adj,
    float* __restrict__ h, float2* __restrict__ hsc, float* __restrict__ ELa,
    int* __restrict__ cnt_g, int2* __restrict__ edge_g) {
    __shared__ float smv[D];
    __shared__ int wcnt[4];
    const int t = threadIdx.x, w = t >> 6, l = t & 63;
    const int g = l >> 4, m = l & 15;
    const int i = blockIdx.x;
    const unsigned long long lt_mask = (1ull << l) - 1ull;

    // issue adj-row segment load early (hides HBM latency under the matvec)
    float4 av = *(const float4*)(adj + (size_t)i * N + (w << 8) + 4 * l);

    // x-row chunks (reused across all 8 matvec passes)
    float4 xa = *(const float4*)(x + (size_t)i * D + 4 * m);
    float4 xb = *(const float4*)(x + (size_t)i * D + 64 + 4 * m);

    float xn2 = group16_sum(xa.x * xa.x + xa.y * xa.y + xa.z * xa.z +
                            xa.w * xa.w + xb.x * xb.x + xb.y * xb.y +
                            xb.z * xb.z + xb.w * xb.w);

    // matvec: wave w covers outputs [32w,32w+32); group g does output 32w+4p+g
#pragma unroll
    for (int p = 0; p < 8; ++p) {
        const int o = (w << 5) + (p << 2) + g;
        float4 wa = *(const float4*)(Wm + (size_t)o * D + 4 * m);
        float4 wb = *(const float4*)(Wm + (size_t)o * D + 64 + 4 * m);
        float s = xa.x * wa.x + xa.y * wa.y + xa.z * wa.z + xa.w * wa.w +
                  xb.x * wb.x + xb.y * wb.y + xb.z * wb.z + xb.w * wb.w;
        s = group16_sum(s);
        if (m == 0) smv[o] = s;
    }

    // ballot compaction bookkeeping
    float ae[4] = {av.x, av.y, av.z, av.w};
    unsigned long long msk[4];
    int cnt = 0;
#pragma unroll
    for (int e = 0; e < 4; ++e) {
        msk[e] = __ballot(ae[e] != 0.0f);
        cnt += __popcll(msk[e]);
    }
    if (l == 0) wcnt[w] = cnt;
    __syncthreads();  // [A] publishes smv and wcnt

    int base = 0;
#pragma unroll
    for (int ww = 0; ww < 4; ++ww)
        if (ww < w) base += wcnt[ww];
    const int tot = wcnt[0] + wcnt[1] + wcnt[2] + wcnt[3];
    {
        int off = base;
#pragma unroll
        for (int e = 0; e < 4; ++e) {
            if (ae[e] != 0.0f) {
                int pos = off + __popcll(msk[e] & lt_mask);
                if (pos < CAP)
                    edge_g[i * CAP + pos] =
                        make_int2((w << 8) + 4 * l + e, __float_as_int(ae[e]));
            }
            off += __popcll(msk[e]);
        }
    }
    if (t == 0) cnt_g[i] = (tot < CAP) ? tot : CAP;

    if (w != 0) return;

    // ---- wave 0: bias chain + mobius scalar chain (3 serial reduction stages)
    const float attb = attb_p[0];
    float2 bv = *(const float2*)(bias + 2 * l);
    float2 mv = *(const float2*)(&smv[2 * l]);

    // stage 1: (|mv|^2, |bias|^2) batched
    float mxn2 = mv.x * mv.x + mv.y * mv.y;
    float bn2 = bv.x * bv.x + bv.y * bv.y;
    wave_sum2(mxn2, bn2);

    float bn = fmaxf(sqrtf(bn2), MINN);
    float tb = tanhf(bn);
    float bs = tb / bn;
    float2 hbv = make_float2(bs * bv.x, bs * bv.y);
    float vn = tb;  // |expmap0(bias)| = tanh(|bias|)
    if (vn > MAXNORM) {
        float sc0 = MAXNORM / vn;
        hbv.x *= sc0; hbv.y *= sc0;
        vn = MAXNORM;
    }
    float y2 = vn * vn;

    float mxn = fmaxf(sqrtf(mxn2), MINN);
    float xn = fmaxf(sqrtf(xn2), MINN);
    float rn = tanhf(mxn / xn * artanh_fast(xn));  // = |mobius_matvec| >= 0
    float sc = rn / mxn;
    float r0 = sc * mv.x, r1 = sc * mv.y;
    float sr = (rn > MAXNORM) ? (MAXNORM / rn) : 1.f;
    r0 *= sr; r1 *= sr;
    float rn_c = rn * sr;
    float x2 = rn_c * rn_c;

    // stage 2: <r, hb>
    float xy = wave_sum(r0 * hbv.x + r1 * hbv.y);
    float den = fmaxf(1.f + 2.f * xy + x2 * y2, MINN);
    float ca = (1.f + 2.f * xy + y2) / den;
    float cb = (1.f - x2) / den;
    float hp0 = ca * r0 + cb * hbv.x;
    float hp1 = ca * r1 + cb * hbv.y;

    // stage 3: (|hp|^2, hp.wl, hp.wr) batched on UNSCALED hp (proj is linear)
    float t0 = hp0 * hp0 + hp1 * hp1;
    float t1 = hp0 * attw[2 * l] + hp1 * attw[2 * l + 1];
    float t2 = hp0 * attw[D + 2 * l] + hp1 * attw[D + 2 * l + 1];
    wave_sum3(t0, t1, t2);

    float hn = fmaxf(sqrtf(t0), MINN);
    float sh = (hn > MAXNORM) ? (MAXNORM / hn) : 1.f;
    hp0 *= sh; hp1 *= sh;
    float h2 = t0 * sh * sh;
    float hnn = fmaxf(sqrtf(h2), MINN);
    float fac = artanh_fast(hnn) / hnn;
    float sLv = fac * (t1 * sh);
    float sRv = fac * (t2 * sh);

    *(float2*)(h + (size_t)i * D + 2 * l) = make_float2(hp0, hp1);
    if (l == 0) {
        hsc[i] = make_float2(h2, __expf(-sRv));
        ELa[i] = __expf(-(sLv + attb));
    }
}

// ---- kernel B: sparse aggregation + epilogue. One block per row i.
// 32 groups of 8 lanes; group gid handles neighbors n = gid, gid+32, ...
// (typical degree ~20 -> ONE round). Lane m owns dims [16m, 16m+16).
__global__ __launch_bounds__(256) void k_agg(
    const float* __restrict__ h, const float2* __restrict__ hsc,
    const float* __restrict__ ELa, const int* __restrict__ cnt_g,
    const int2* __restrict__ edge_g, float* __restrict__ out) {
    __shared__ __align__(16) float accS[32][132];
    __shared__ float sAs[32];

    const int t = threadIdx.x, w = t >> 6, l = t & 63;
    const int gid = t >> 3, m = t & 7;
    const int i = blockIdx.x;

    const int tot = cnt_g[i];
    const float2 qi = hsc[i];
    const float h2_i = qi.x;
    const float EL_i = ELa[i];
    const float B = 1.f - h2_i;
    const float cA = fmaxf(B, MINN);

    const float* hrow = h + (size_t)i * D + 16 * m;
    float4 hi0 = *(const float4*)(hrow);
    float4 hi1 = *(const float4*)(hrow + 4);
    float4 hi2 = *(const float4*)(hrow + 8);
    float4 hi3 = *(const float4*)(hrow + 12);

    float4 a0 = make_float4(0.f, 0.f, 0.f, 0.f);
    float4 a1 = make_float4(0.f, 0.f, 0.f, 0.f);
    float4 a2 = make_float4(0.f, 0.f, 0.f, 0.f);
    float4 a3 = make_float4(0.f, 0.f, 0.f, 0.f);
    float sAcc = 0.f;

    for (int n = gid; n < tot; n += 32) {
        int2 e = edge_g[i * CAP + n];
        const int j = e.x;
        const float aval = __int_as_float(e.y);
        const float* hj = h + (size_t)j * D + 16 * m;
        float4 hj0 = *(const float4*)(hj);
        float4 hj1 = *(const float4*)(hj + 4);
        float4 hj2 = *(const float4*)(hj + 8);
        float4 hj3 = *(const float4*)(hj + 12);
        float2 qj = hsc[j];

        float d = hi0.x * hj0.x + hi0.y * hj0.y + hi0.z * hj0.z +
                  hi0.w * hj0.w + hi1.x * hj1.x + hi1.y * hj1.y +
                  hi1.z * hj1.z + hi1.w * hj1.w + hi2.x * hj2.x +
                  hi2.y * hj2.y + hi2.z * hj2.z + hi2.w * hj2.w +
                  hi3.x * hj3.x + hi3.y * hj3.y + hi3.z * hj3.z +
                  hi3.w * hj3.w;
        float dot = group8_sum(d);
        float h2_j = qj.x, ER_j = qj.y;
        float den = fmaxf(1.f - 2.f * dot + h2_i * h2_j, MINN);
        float p = __fdividef(-(1.f - 2.f * dot + h2_j), den);
        float qq = __fdividef(B, den);
        float n2 = p * p * h2_i + 2.f * p * qq * dot + qq * qq * h2_j;
        float nrm = fmaxf(sqrtf(fmaxf(n2, 0.f)), MINN);
        float coefc = cA * __fdividef(artanh_fast(nrm), nrm);
        float sig = __fdividef(1.f, 1.f + EL_i * ER_j);
        float wgt = aval * sig;
        sAcc += wgt * coefc * p;
        float wb = wgt * coefc * qq;
        a0.x += wb * hj0.x; a0.y += wb * hj0.y;
        a0.z += wb * hj0.z; a0.w += wb * hj0.w;
        a1.x += wb * hj1.x; a1.y += wb * hj1.y;
        a1.z += wb * hj1.z; a1.w += wb * hj1.w;
        a2.x += wb * hj2.x; a2.y += wb * hj2.y;
        a2.z += wb * hj2.z; a2.w += wb * hj2.w;
        a3.x += wb * hj3.x; a3.y += wb * hj3.y;
        a3.z += wb * hj3.z; a3.w += wb * hj3.w;
    }

    *(float4*)(&accS[gid][16 * m]) = a0;
    *(float4*)(&accS[gid][16 * m + 4]) = a1;
    *(float4*)(&accS[gid][16 * m + 8]) = a2;
    *(float4*)(&accS[gid][16 * m + 12]) = a3;
    if (m == 0) sAs[gid] = sAcc;
    __syncthreads();

    if (w != 0) return;

    // ---- wave 0 epilogue: lane l owns dims (2l, 2l+1)
    float b0 = 0.f, b1 = 0.f, sA = 0.f;
#pragma unroll
    for (int g2 = 0; g2 < 32; ++g2) {
        b0 += accS[g2][2 * l];
        b1 += accS[g2][2 * l + 1];
        sA += sAs[g2];
    }

    float2 hi = *(const float2*)(h + (size_t)i * D + 2 * l);
    float u0 = sA * hi.x + b0, u1 = sA * hi.y + b1;

    float u2 = u0 * u0 + u1 * u1;
    float hiu = hi.x * u0 + hi.y * u1;
    wave_sum2(u2, hiu);
    float un = fmaxf(sqrtf(u2), MINN);
    float lam = 2.f / cA;
    float th = tanhf(0.5f * lam * un);
    float r = th / un;
    float s0 = r * u0, s1 = r * u1;
    float y2 = th * th;
    float xy = r * hiu;
    float den2 = fmaxf(1.f + 2.f * xy + h2_i * y2, MINN);
    float c1 = (1.f + 2.f * xy + y2) / den2;
    float c2 = (1.f - h2_i) / den2;
    float hp0 = c1 * hi.x + c2 * s0;
    float hp1 = c1 * hi.y + c2 * s1;
    float hn2 = wave_sum(hp0 * hp0 + hp1 * hp1);
    float hn = fmaxf(sqrtf(hn2), MINN);
    float scl = (hn > MAXNORM) ? (MAXNORM / hn) : 1.f;
    hp0 *= scl; hp1 *= scl;
    float n3 = fminf(fmaxf(hn, MINN), MAXNORM);
    float fac = tanhf(n3) / n3;
    float o0 = fac * hp0, o1 = fac * hp1;
    float onrm = tanhf(n3);
    if (onrm > MAXNORM) {
        float ss = MAXNORM / onrm;
        o0 *= ss; o1 *= ss;
    }
    *(float2*)(out + (size_t)i * D + 2 * l) = make_float2(o0, o1);
}

extern "C" void kernel_launch(void* const* d_in, const int* in_sizes, int n_in,
                              void* d_out, int out_size, void* d_ws, size_t ws_size,
                              hipStream_t stream) {
    const float* x = (const float*)d_in[0];
    const float* adj = (const float*)d_in[1];
    const float* Wm = (const float*)d_in[2];
    const float* bias = (const float*)d_in[3];
    const float* attw = (const float*)d_in[4];
    const float* attb = (const float*)d_in[5];
    float* out = (float*)d_out;

    float* ws = (float*)d_ws;
    float* h = ws;                                   // N*D floats
    float2* hsc = (float2*)(h + (size_t)N * D);      // N float2 (h2, e^-sR)
    float* ELa = (float*)(hsc + N);                  // N floats e^-(sL+attb)
    int* cnt_g = (int*)(ELa + N);                    // N ints
    int2* edge_g = (int2*)(cnt_g + N);               // N*CAP int2 (j, aval)

    hipLaunchKernelGGL(k_rows, dim3(N), dim3(256), 0, stream, x, Wm, bias,
                       attw, attb, adj, h, hsc, ELa, cnt_g, edge_g);
    hipLaunchKernelGGL(k_agg, dim3(N), dim3(256), 0, stream, h, hsc, ELa,
                       cnt_g, edge_g, out);
}

// Round 12
// 17.091 us; speedup vs baseline: 4.7004x; 1.0198x over previous
//
#include <hip/hip_runtime.h>
#include <math.h>

#define N 1024
#define D 128
#define CAP 96
#define MAXNORM 0.996f
#define MINN 1e-15f

__device__ __forceinline__ float wave_sum(float v) {
#pragma unroll
    for (int o = 32; o > 0; o >>= 1) v += __shfl_xor(v, o, 64);
    return v;
}

__device__ __forceinline__ void wave_sum2(float& a, float& b) {
#pragma unroll
    for (int o = 32; o > 0; o >>= 1) {
        a += __shfl_xor(a, o, 64);
        b += __shfl_xor(b, o, 64);
    }
}

__device__ __forceinline__ void wave_sum3(float& a, float& b, float& c) {
#pragma unroll
    for (int o = 32; o > 0; o >>= 1) {
        a += __shfl_xor(a, o, 64);
        b += __shfl_xor(b, o, 64);
        c += __shfl_xor(c, o, 64);
    }
}

__device__ __forceinline__ float group16_sum(float v) {
#pragma unroll
    for (int o = 8; o > 0; o >>= 1) v += __shfl_xor(v, o, 64);
    return v;
}

__device__ __forceinline__ float group8_sum(float v) {
#pragma unroll
    for (int o = 4; o > 0; o >>= 1) v += __shfl_xor(v, o, 64);
    return v;
}

__device__ __forceinline__ float artanh_fast(float x) {
    x = fminf(fmaxf(x, -1.0f + 1e-7f), 1.0f - 1e-7f);
    return 0.5f * __logf(__fdividef(1.0f + x, 1.0f - x));
}

// ---- kernel A: one block (4 waves) per row i.
// h row, packed (h2, e^-sR), e^-(sL+attb), and adj-row CSR (cnt / packed edges).
__global__ __launch_bounds__(256) void k_rows(
    const float* __restrict__ x, const float* __restrict__ Wm,
    const float* __restrict__ bias, const float* __restrict__ attw,
    const float* __restrict__ attb_p, const float* __restrict__ adj,
    float* __restrict__ h, float2* __restrict__ hsc, float* __restrict__ ELa,
    int* __restrict__ cnt_g, int2* __restrict__ edge_g) {
    __shared__ float smv[D];
    __shared__ int wcnt[4];
    const int t = threadIdx.x, w = t >> 6, l = t & 63;
    const int g = l >> 4, m = l & 15;
    const int i = blockIdx.x;
    const unsigned long long lt_mask = (1ull << l) - 1ull;

    // issue adj-row segment load early (hides HBM latency under the matvec)
    float4 av = *(const float4*)(adj + (size_t)i * N + (w << 8) + 4 * l);

    // x-row chunks (reused across all 8 matvec passes)
    float4 xa = *(const float4*)(x + (size_t)i * D + 4 * m);
    float4 xb = *(const float4*)(x + (size_t)i * D + 64 + 4 * m);

    float xn2 = group16_sum(xa.x * xa.x + xa.y * xa.y + xa.z * xa.z +
                            xa.w * xa.w + xb.x * xb.x + xb.y * xb.y +
                            xb.z * xb.z + xb.w * xb.w);

    // matvec: wave w covers outputs [32w,32w+32); group g does output 32w+4p+g
#pragma unroll
    for (int p = 0; p < 8; ++p) {
        const int o = (w << 5) + (p << 2) + g;
        float4 wa = *(const float4*)(Wm + (size_t)o * D + 4 * m);
        float4 wb = *(const float4*)(Wm + (size_t)o * D + 64 + 4 * m);
        float s = xa.x * wa.x + xa.y * wa.y + xa.z * wa.z + xa.w * wa.w +
                  xb.x * wb.x + xb.y * wb.y + xb.z * wb.z + xb.w * wb.w;
        s = group16_sum(s);
        if (m == 0) smv[o] = s;
    }

    // ballot compaction bookkeeping
    float ae[4] = {av.x, av.y, av.z, av.w};
    unsigned long long msk[4];
    int cnt = 0;
#pragma unroll
    for (int e = 0; e < 4; ++e) {
        msk[e] = __ballot(ae[e] != 0.0f);
        cnt += __popcll(msk[e]);
    }
    if (l == 0) wcnt[w] = cnt;
    __syncthreads();  // [A] publishes smv and wcnt

    int base = 0;
#pragma unroll
    for (int ww = 0; ww < 4; ++ww)
        if (ww < w) base += wcnt[ww];
    const int tot = wcnt[0] + wcnt[1] + wcnt[2] + wcnt[3];
    {
        int off = base;
#pragma unroll
        for (int e = 0; e < 4; ++e) {
            if (ae[e] != 0.0f) {
                int pos = off + __popcll(msk[e] & lt_mask);
                if (pos < CAP)
                    edge_g[i * CAP + pos] =
                        make_int2((w << 8) + 4 * l + e, __float_as_int(ae[e]));
            }
            off += __popcll(msk[e]);
        }
    }
    if (t == 0) cnt_g[i] = (tot < CAP) ? tot : CAP;

    if (w != 0) return;

    // ---- wave 0: TWO serial reduction stages total.
    const float attb = attb_p[0];
    float2 bv = *(const float2*)(bias + 2 * l);
    float2 mv = *(const float2*)(&smv[2 * l]);

    // stage 1: (|mv|^2, |bias|^2, <mv,bias>) batched
    float mxn2 = mv.x * mv.x + mv.y * mv.y;
    float bn2 = bv.x * bv.x + bv.y * bv.y;
    float mvb = mv.x * bv.x + mv.y * bv.y;
    wave_sum3(mxn2, bn2, mvb);

    // bias chain (all scalar): hbv = hbs * bv
    float bn = fmaxf(sqrtf(bn2), MINN);
    float tb = tanhf(bn);
    float bsc = tb / bn;
    float clampB = (tb > MAXNORM) ? (MAXNORM / tb) : 1.f;
    float hbs = bsc * clampB;
    float vn = fminf(tb, MAXNORM);
    float y2 = vn * vn;

    // mobius_matvec norm chain (scalar): r = rs * mv
    float mxn = fmaxf(sqrtf(mxn2), MINN);
    float xn = fmaxf(sqrtf(xn2), MINN);
    float rn = tanhf(mxn / xn * artanh_fast(xn));  // = |mobius_matvec| >= 0
    float rsc = rn / mxn;
    float sr = (rn > MAXNORM) ? (MAXNORM / rn) : 1.f;
    float rs = rsc * sr;
    float rn_c = rn * sr;
    float x2 = rn_c * rn_c;

    // mobius_add(r, hbv): <r,hbv> = rs*hbs*<mv,bv> (scalar — no reduction)
    float xy = rs * hbs * mvb;
    float den = fmaxf(1.f + 2.f * xy + x2 * y2, MINN);
    float ca = (1.f + 2.f * xy + y2) / den;
    float cb = (1.f - x2) / den;
    float hp0 = ca * rs * mv.x + cb * hbs * bv.x;
    float hp1 = ca * rs * mv.y + cb * hbs * bv.y;

    // stage 2: (|hp|^2, hp.wl, hp.wr) batched on UNSCALED hp (proj is linear)
    float t0 = hp0 * hp0 + hp1 * hp1;
    float t1 = hp0 * attw[2 * l] + hp1 * attw[2 * l + 1];
    float t2 = hp0 * attw[D + 2 * l] + hp1 * attw[D + 2 * l + 1];
    wave_sum3(t0, t1, t2);

    float hn = fmaxf(sqrtf(t0), MINN);
    float sh = (hn > MAXNORM) ? (MAXNORM / hn) : 1.f;
    hp0 *= sh; hp1 *= sh;
    float h2 = t0 * sh * sh;
    float hnn = fmaxf(sqrtf(h2), MINN);
    float fac = artanh_fast(hnn) / hnn;
    float sLv = fac * (t1 * sh);
    float sRv = fac * (t2 * sh);

    *(float2*)(h + (size_t)i * D + 2 * l) = make_float2(hp0, hp1);
    if (l == 0) {
        hsc[i] = make_float2(h2, __expf(-sRv));
        ELa[i] = __expf(-(sLv + attb));
    }
}

// ---- kernel B: sparse aggregation + epilogue. One block per row i.
// 32 groups of 8 lanes; group gid handles neighbors n = gid, gid+32, ...
// (typical degree ~20 -> ONE round). Lane m owns dims [16m, 16m+16).
__global__ __launch_bounds__(256) void k_agg(
    const float* __restrict__ h, const float2* __restrict__ hsc,
    const float* __restrict__ ELa, const int* __restrict__ cnt_g,
    const int2* __restrict__ edge_g, float* __restrict__ out) {
    __shared__ __align__(16) float accS[32][132];
    __shared__ float sAs[32];

    const int t = threadIdx.x, w = t >> 6, l = t & 63;
    const int gid = t >> 3, m = t & 7;
    const int i = blockIdx.x;

    const int tot = cnt_g[i];
    const float2 qi = hsc[i];
    const float h2_i = qi.x;
    const float EL_i = ELa[i];
    const float B = 1.f - h2_i;
    const float cA = fmaxf(B, MINN);

    const float* hrow = h + (size_t)i * D + 16 * m;
    float4 hi0 = *(const float4*)(hrow);
    float4 hi1 = *(const float4*)(hrow + 4);
    float4 hi2 = *(const float4*)(hrow + 8);
    float4 hi3 = *(const float4*)(hrow + 12);

    float4 a0 = make_float4(0.f, 0.f, 0.f, 0.f);
    float4 a1 = make_float4(0.f, 0.f, 0.f, 0.f);
    float4 a2 = make_float4(0.f, 0.f, 0.f, 0.f);
    float4 a3 = make_float4(0.f, 0.f, 0.f, 0.f);
    float sAcc = 0.f;

    for (int n = gid; n < tot; n += 32) {
        int2 e = edge_g[i * CAP + n];
        const int j = e.x;
        const float aval = __int_as_float(e.y);
        const float* hj = h + (size_t)j * D + 16 * m;
        float4 hj0 = *(const float4*)(hj);
        float4 hj1 = *(const float4*)(hj + 4);
        float4 hj2 = *(const float4*)(hj + 8);
        float4 hj3 = *(const float4*)(hj + 12);
        float2 qj = hsc[j];

        float d = hi0.x * hj0.x + hi0.y * hj0.y + hi0.z * hj0.z +
                  hi0.w * hj0.w + hi1.x * hj1.x + hi1.y * hj1.y +
                  hi1.z * hj1.z + hi1.w * hj1.w + hi2.x * hj2.x +
                  hi2.y * hj2.y + hi2.z * hj2.z + hi2.w * hj2.w +
                  hi3.x * hj3.x + hi3.y * hj3.y + hi3.z * hj3.z +
                  hi3.w * hj3.w;
        float dot = group8_sum(d);
        float h2_j = qj.x, ER_j = qj.y;
        float den = fmaxf(1.f - 2.f * dot + h2_i * h2_j, MINN);
        float p = __fdividef(-(1.f - 2.f * dot + h2_j), den);
        float qq = __fdividef(B, den);
        float n2 = p * p * h2_i + 2.f * p * qq * dot + qq * qq * h2_j;
        float nrm = fmaxf(sqrtf(fmaxf(n2, 0.f)), MINN);
        float coefc = cA * __fdividef(artanh_fast(nrm), nrm);
        float sig = __fdividef(1.f, 1.f + EL_i * ER_j);
        float wgt = aval * sig;
        sAcc += wgt * coefc * p;
        float wb = wgt * coefc * qq;
        a0.x += wb * hj0.x; a0.y += wb * hj0.y;
        a0.z += wb * hj0.z; a0.w += wb * hj0.w;
        a1.x += wb * hj1.x; a1.y += wb * hj1.y;
        a1.z += wb * hj1.z; a1.w += wb * hj1.w;
        a2.x += wb * hj2.x; a2.y += wb * hj2.y;
        a2.z += wb * hj2.z; a2.w += wb * hj2.w;
        a3.x += wb * hj3.x; a3.y += wb * hj3.y;
        a3.z += wb * hj3.z; a3.w += wb * hj3.w;
    }

    *(float4*)(&accS[gid][16 * m]) = a0;
    *(float4*)(&accS[gid][16 * m + 4]) = a1;
    *(float4*)(&accS[gid][16 * m + 8]) = a2;
    *(float4*)(&accS[gid][16 * m + 12]) = a3;
    if (m == 0) sAs[gid] = sAcc;
    __syncthreads();

    if (w != 0) return;

    // ---- wave 0 epilogue: lane l owns dims (2l, 2l+1); ONE reduction total
    float b0 = 0.f, b1 = 0.f, sA = 0.f;
#pragma unroll
    for (int g2 = 0; g2 < 32; ++g2) {
        b0 += accS[g2][2 * l];
        b1 += accS[g2][2 * l + 1];
        sA += sAs[g2];
    }

    float2 hi = *(const float2*)(h + (size_t)i * D + 2 * l);
    float u0 = sA * hi.x + b0, u1 = sA * hi.y + b1;

    float u2 = u0 * u0 + u1 * u1;
    float hiu = hi.x * u0 + hi.y * u1;
    wave_sum2(u2, hiu);
    float un = fmaxf(sqrtf(u2), MINN);
    float lam = 2.f / cA;
    float th = tanhf(0.5f * lam * un);
    float r = th / un;
    float s0 = r * u0, s1 = r * u1;
    float y2 = th * th;
    float xy = r * hiu;
    float den2 = fmaxf(1.f + 2.f * xy + h2_i * y2, MINN);
    float c1 = (1.f + 2.f * xy + y2) / den2;
    float c2 = (1.f - h2_i) / den2;
    float hp0 = c1 * hi.x + c2 * s0;
    float hp1 = c1 * hi.y + c2 * s1;
    // |hp|^2 analytically: <hi,s> = xy, |s|^2 = y2 — no reduction needed
    float hn2 = c1 * c1 * h2_i + 2.f * c1 * c2 * xy + c2 * c2 * y2;
    float hn = fmaxf(sqrtf(hn2), MINN);
    float scl = (hn > MAXNORM) ? (MAXNORM / hn) : 1.f;
    hp0 *= scl; hp1 *= scl;
    float n3 = fminf(fmaxf(hn, MINN), MAXNORM);
    float fac = tanhf(n3) / n3;
    float o0 = fac * hp0, o1 = fac * hp1;
    float onrm = tanhf(n3);
    if (onrm > MAXNORM) {
        float ss = MAXNORM / onrm;
        o0 *= ss; o1 *= ss;
    }
    *(float2*)(out + (size_t)i * D + 2 * l) = make_float2(o0, o1);
}

extern "C" void kernel_launch(void* const* d_in, const int* in_sizes, int n_in,
                              void* d_out, int out_size, void* d_ws, size_t ws_size,
                              hipStream_t stream) {
    const float* x = (const float*)d_in[0];
    const float* adj = (const float*)d_in[1];
    const float* Wm = (const float*)d_in[2];
    const float* bias = (const float*)d_in[3];
    const float* attw = (const float*)d_in[4];
    const float* attb = (const float*)d_in[5];
    float* out = (float*)d_out;

    float* ws = (float*)d_ws;
    float* h = ws;                                   // N*D floats
    float2* hsc = (float2*)(h + (size_t)N * D);      // N float2 (h2, e^-sR)
    float* ELa = (float*)(hsc + N);                  // N floats e^-(sL+attb)
    int* cnt_g = (int*)(ELa + N);                    // N ints
    int2* edge_g = (int2*)(cnt_g + N);               // N*CAP int2 (j, aval)

    hipLaunchKernelGGL(k_rows, dim3(N), dim3(256), 0, stream, x, Wm, bias,
                       attw, attb, adj, h, hsc, ELa, cnt_g, edge_g);
    hipLaunchKernelGGL(k_agg, dim3(N), dim3(256), 0, stream, h, hsc, ELa,
                       cnt_g, edge_g, out);
}

// Round 13
// 16.606 us; speedup vs baseline: 4.8377x; 1.0292x over previous
//
#include <hip/hip_runtime.h>
#include <math.h>

#define N 1024
#define D 128
#define CAP 96
#define MAXNORM 0.996f
#define MINN 1e-15f

__device__ __forceinline__ float wave_sum(float v) {
#pragma unroll
    for (int o = 32; o > 0; o >>= 1) v += __shfl_xor(v, o, 64);
    return v;
}

__device__ __forceinline__ void wave_sum2(float& a, float& b) {
#pragma unroll
    for (int o = 32; o > 0; o >>= 1) {
        a += __shfl_xor(a, o, 64);
        b += __shfl_xor(b, o, 64);
    }
}

__device__ __forceinline__ void wave_sum3(float& a, float& b, float& c) {
#pragma unroll
    for (int o = 32; o > 0; o >>= 1) {
        a += __shfl_xor(a, o, 64);
        b += __shfl_xor(b, o, 64);
        c += __shfl_xor(c, o, 64);
    }
}

__device__ __forceinline__ float group16_sum(float v) {
#pragma unroll
    for (int o = 8; o > 0; o >>= 1) v += __shfl_xor(v, o, 64);
    return v;
}

__device__ __forceinline__ float group8_sum(float v) {
#pragma unroll
    for (int o = 4; o > 0; o >>= 1) v += __shfl_xor(v, o, 64);
    return v;
}

__device__ __forceinline__ float artanh_fast(float x) {
    x = fminf(fmaxf(x, -1.0f + 1e-7f), 1.0f - 1e-7f);
    return 0.5f * __logf(__fdividef(1.0f + x, 1.0f - x));
}

// tanh for x >= 0 via one v_exp: (1 - e^-2x) / (1 + e^-2x)
__device__ __forceinline__ float tanh_pos(float x) {
    float t = __expf(-2.f * x);
    return __fdividef(1.f - t, 1.f + t);
}

// ---- kernel A: one block (4 waves) per row i.
// h row, rowmeta = (h2, e^-sR, e^-(sL+attb), cnt), adj-row CSR edges.
__global__ __launch_bounds__(256) void k_rows(
    const float* __restrict__ x, const float* __restrict__ Wm,
    const float* __restrict__ bias, const float* __restrict__ attw,
    const float* __restrict__ attb_p, const float* __restrict__ adj,
    float* __restrict__ h, float4* __restrict__ rowmeta,
    int2* __restrict__ edge_g) {
    __shared__ float smv[D];
    __shared__ int wcnt[4];
    const int t = threadIdx.x, w = t >> 6, l = t & 63;
    const int g = l >> 4, m = l & 15;
    const int i = blockIdx.x;
    const unsigned long long lt_mask = (1ull << l) - 1ull;

    // issue adj-row segment load early (hides HBM latency under the matvec)
    float4 av = *(const float4*)(adj + (size_t)i * N + (w << 8) + 4 * l);

    // x-row chunks (reused across all 8 matvec passes)
    float4 xa = *(const float4*)(x + (size_t)i * D + 4 * m);
    float4 xb = *(const float4*)(x + (size_t)i * D + 64 + 4 * m);

    float xn2 = group16_sum(xa.x * xa.x + xa.y * xa.y + xa.z * xa.z +
                            xa.w * xa.w + xb.x * xb.x + xb.y * xb.y +
                            xb.z * xb.z + xb.w * xb.w);

    // matvec: wave w covers outputs [32w,32w+32); group g does output 32w+4p+g
#pragma unroll
    for (int p = 0; p < 8; ++p) {
        const int o = (w << 5) + (p << 2) + g;
        float4 wa = *(const float4*)(Wm + (size_t)o * D + 4 * m);
        float4 wb = *(const float4*)(Wm + (size_t)o * D + 64 + 4 * m);
        float s = xa.x * wa.x + xa.y * wa.y + xa.z * wa.z + xa.w * wa.w +
                  xb.x * wb.x + xb.y * wb.y + xb.z * wb.z + xb.w * wb.w;
        s = group16_sum(s);
        if (m == 0) smv[o] = s;
    }

    // ballot compaction bookkeeping
    float ae[4] = {av.x, av.y, av.z, av.w};
    unsigned long long msk[4];
    int cnt = 0;
#pragma unroll
    for (int e = 0; e < 4; ++e) {
        msk[e] = __ballot(ae[e] != 0.0f);
        cnt += __popcll(msk[e]);
    }
    if (l == 0) wcnt[w] = cnt;
    __syncthreads();  // [A] publishes smv and wcnt

    int base = 0;
#pragma unroll
    for (int ww = 0; ww < 4; ++ww)
        if (ww < w) base += wcnt[ww];
    const int tot = wcnt[0] + wcnt[1] + wcnt[2] + wcnt[3];
    {
        int off = base;
#pragma unroll
        for (int e = 0; e < 4; ++e) {
            if (ae[e] != 0.0f) {
                int pos = off + __popcll(msk[e] & lt_mask);
                if (pos < CAP)
                    edge_g[i * CAP + pos] =
                        make_int2((w << 8) + 4 * l + e, __float_as_int(ae[e]));
            }
            off += __popcll(msk[e]);
        }
    }

    if (w != 0) return;

    // ---- wave 0: TWO serial reduction stages total.
    const float attb = attb_p[0];
    float2 bv = *(const float2*)(bias + 2 * l);
    float2 mv = *(const float2*)(&smv[2 * l]);

    // stage 1: (|mv|^2, |bias|^2, <mv,bias>) batched
    float mxn2 = mv.x * mv.x + mv.y * mv.y;
    float bn2 = bv.x * bv.x + bv.y * bv.y;
    float mvb = mv.x * bv.x + mv.y * bv.y;
    wave_sum3(mxn2, bn2, mvb);

    // bias chain (all scalar): hbv = hbs * bv
    float bn = fmaxf(sqrtf(bn2), MINN);
    float tb = tanh_pos(bn);
    float bsc = tb / bn;
    float clampB = (tb > MAXNORM) ? (MAXNORM / tb) : 1.f;
    float hbs = bsc * clampB;
    float vn = fminf(tb, MAXNORM);
    float y2 = vn * vn;

    // mobius_matvec norm chain (scalar): r = rs * mv
    float mxn = fmaxf(sqrtf(mxn2), MINN);
    float xn = fmaxf(sqrtf(xn2), MINN);
    float rn = tanh_pos(mxn / xn * artanh_fast(xn));  // = |mobius_matvec| >= 0
    float rsc = rn / mxn;
    float sr = (rn > MAXNORM) ? (MAXNORM / rn) : 1.f;
    float rs = rsc * sr;
    float rn_c = rn * sr;
    float x2 = rn_c * rn_c;

    // mobius_add(r, hbv): <r,hbv> = rs*hbs*<mv,bv> (scalar — no reduction)
    float xy = rs * hbs * mvb;
    float den = fmaxf(1.f + 2.f * xy + x2 * y2, MINN);
    float ca = (1.f + 2.f * xy + y2) / den;
    float cb = (1.f - x2) / den;
    float hp0 = ca * rs * mv.x + cb * hbs * bv.x;
    float hp1 = ca * rs * mv.y + cb * hbs * bv.y;

    // stage 2: (|hp|^2, hp.wl, hp.wr) batched on UNSCALED hp (proj is linear)
    float t0 = hp0 * hp0 + hp1 * hp1;
    float t1 = hp0 * attw[2 * l] + hp1 * attw[2 * l + 1];
    float t2 = hp0 * attw[D + 2 * l] + hp1 * attw[D + 2 * l + 1];
    wave_sum3(t0, t1, t2);

    float hn = fmaxf(sqrtf(t0), MINN);
    float sh = (hn > MAXNORM) ? (MAXNORM / hn) : 1.f;
    hp0 *= sh; hp1 *= sh;
    float h2 = t0 * sh * sh;
    float hnn = fmaxf(sqrtf(h2), MINN);
    float fac = artanh_fast(hnn) / hnn;
    float sLv = fac * (t1 * sh);
    float sRv = fac * (t2 * sh);

    *(float2*)(h + (size_t)i * D + 2 * l) = make_float2(hp0, hp1);
    if (l == 0) {
        int cl = (tot < CAP) ? tot : CAP;
        rowmeta[i] = make_float4(h2, __expf(-sRv), __expf(-(sLv + attb)),
                                 __int_as_float(cl));
    }
}

// ---- kernel B: sparse aggregation + epilogue. One block per row i.
// 32 groups of 8 lanes; group gid handles neighbors n = gid, gid+32, ...
// (typical degree ~20 -> ONE round). Lane m owns dims [16m, 16m+16).
__global__ __launch_bounds__(256) void k_agg(
    const float* __restrict__ h, const float4* __restrict__ rowmeta,
    const int2* __restrict__ edge_g, float* __restrict__ out) {
    __shared__ __align__(16) float accS[32][132];
    __shared__ float sAs[32];
    __shared__ __align__(8) float accW[4][130];
    __shared__ float sAw[4];

    const int t = threadIdx.x, w = t >> 6, l = t & 63;
    const int gid = t >> 3, m = t & 7;
    const int i = blockIdx.x;

    const float4 rm = rowmeta[i];
    const int tot = __float_as_int(rm.w);
    const float h2_i = rm.x;
    const float EL_i = rm.z;
    const float B = 1.f - h2_i;
    const float cA = fmaxf(B, MINN);

    const float* hrow = h + (size_t)i * D + 16 * m;
    float4 hi0 = *(const float4*)(hrow);
    float4 hi1 = *(const float4*)(hrow + 4);
    float4 hi2 = *(const float4*)(hrow + 8);
    float4 hi3 = *(const float4*)(hrow + 12);

    float4 a0 = make_float4(0.f, 0.f, 0.f, 0.f);
    float4 a1 = make_float4(0.f, 0.f, 0.f, 0.f);
    float4 a2 = make_float4(0.f, 0.f, 0.f, 0.f);
    float4 a3 = make_float4(0.f, 0.f, 0.f, 0.f);
    float sAcc = 0.f;

    for (int n = gid; n < tot; n += 32) {
        int2 e = edge_g[i * CAP + n];
        const int j = e.x;
        const float aval = __int_as_float(e.y);
        const float* hj = h + (size_t)j * D + 16 * m;
        float4 hj0 = *(const float4*)(hj);
        float4 hj1 = *(const float4*)(hj + 4);
        float4 hj2 = *(const float4*)(hj + 8);
        float4 hj3 = *(const float4*)(hj + 12);
        float2 qj = *(const float2*)(&rowmeta[j]);  // (h2_j, e^-sR_j)

        float d = hi0.x * hj0.x + hi0.y * hj0.y + hi0.z * hj0.z +
                  hi0.w * hj0.w + hi1.x * hj1.x + hi1.y * hj1.y +
                  hi1.z * hj1.z + hi1.w * hj1.w + hi2.x * hj2.x +
                  hi2.y * hj2.y + hi2.z * hj2.z + hi2.w * hj2.w +
                  hi3.x * hj3.x + hi3.y * hj3.y + hi3.z * hj3.z +
                  hi3.w * hj3.w;
        float dot = group8_sum(d);
        float h2_j = qj.x, ER_j = qj.y;
        float den = fmaxf(1.f - 2.f * dot + h2_i * h2_j, MINN);
        float p = __fdividef(-(1.f - 2.f * dot + h2_j), den);
        float qq = __fdividef(B, den);
        float n2 = p * p * h2_i + 2.f * p * qq * dot + qq * qq * h2_j;
        float nrm = fmaxf(sqrtf(fmaxf(n2, 0.f)), MINN);
        float coefc = cA * __fdividef(artanh_fast(nrm), nrm);
        float sig = __fdividef(1.f, 1.f + EL_i * ER_j);
        float wgt = aval * sig;
        sAcc += wgt * coefc * p;
        float wb = wgt * coefc * qq;
        a0.x += wb * hj0.x; a0.y += wb * hj0.y;
        a0.z += wb * hj0.z; a0.w += wb * hj0.w;
        a1.x += wb * hj1.x; a1.y += wb * hj1.y;
        a1.z += wb * hj1.z; a1.w += wb * hj1.w;
        a2.x += wb * hj2.x; a2.y += wb * hj2.y;
        a2.z += wb * hj2.z; a2.w += wb * hj2.w;
        a3.x += wb * hj3.x; a3.y += wb * hj3.y;
        a3.z += wb * hj3.z; a3.w += wb * hj3.w;
    }

    *(float4*)(&accS[gid][16 * m]) = a0;
    *(float4*)(&accS[gid][16 * m + 4]) = a1;
    *(float4*)(&accS[gid][16 * m + 8]) = a2;
    *(float4*)(&accS[gid][16 * m + 12]) = a3;
    if (m == 0) sAs[gid] = sAcc;
    __syncthreads();

    // ---- stage 1: wave w reduces its 8 groups; lane l owns dims (2l, 2l+1)
    {
        float b0 = 0.f, b1 = 0.f, psA = 0.f;
#pragma unroll
        for (int k = 0; k < 8; ++k) {
            const int g2 = (w << 3) + k;
            float2 v = *(const float2*)(&accS[g2][2 * l]);
            b0 += v.x;
            b1 += v.y;
            psA += sAs[g2];
        }
        *(float2*)(&accW[w][2 * l]) = make_float2(b0, b1);
        if (l == 0) sAw[w] = psA;
    }
    __syncthreads();

    if (w != 0) return;

    // ---- wave 0 epilogue: lane l owns dims (2l, 2l+1); ONE reduction total
    float2 v0 = *(const float2*)(&accW[0][2 * l]);
    float2 v1 = *(const float2*)(&accW[1][2 * l]);
    float2 v2 = *(const float2*)(&accW[2][2 * l]);
    float2 v3 = *(const float2*)(&accW[3][2 * l]);
    float b0 = v0.x + v1.x + v2.x + v3.x;
    float b1 = v0.y + v1.y + v2.y + v3.y;
    float sA = sAw[0] + sAw[1] + sAw[2] + sAw[3];

    float2 hi = *(const float2*)(h + (size_t)i * D + 2 * l);
    float u0 = sA * hi.x + b0, u1 = sA * hi.y + b1;

    float u2 = u0 * u0 + u1 * u1;
    float hiu = hi.x * u0 + hi.y * u1;
    wave_sum2(u2, hiu);
    float un = fmaxf(sqrtf(u2), MINN);
    float lam = 2.f / cA;
    float th = tanh_pos(0.5f * lam * un);
    float r = th / un;
    float s0 = r * u0, s1 = r * u1;
    float y2 = th * th;
    float xy = r * hiu;
    float den2 = fmaxf(1.f + 2.f * xy + h2_i * y2, MINN);
    float c1 = (1.f + 2.f * xy + y2) / den2;
    float c2 = (1.f - h2_i) / den2;
    float hp0 = c1 * hi.x + c2 * s0;
    float hp1 = c1 * hi.y + c2 * s1;
    // |hp|^2 analytically: <hi,s> = xy, |s|^2 = y2 — no reduction needed
    float hn2 = c1 * c1 * h2_i + 2.f * c1 * c2 * xy + c2 * c2 * y2;
    float hn = fmaxf(sqrtf(hn2), MINN);
    float scl = (hn > MAXNORM) ? (MAXNORM / hn) : 1.f;
    hp0 *= scl; hp1 *= scl;
    float n3 = fminf(fmaxf(hn, MINN), MAXNORM);
    float tn3 = tanh_pos(n3);
    float fac = __fdividef(tn3, n3);
    float o0 = fac * hp0, o1 = fac * hp1;
    if (tn3 > MAXNORM) {
        float ss = MAXNORM / tn3;
        o0 *= ss; o1 *= ss;
    }
    *(float2*)(out + (size_t)i * D + 2 * l) = make_float2(o0, o1);
}

extern "C" void kernel_launch(void* const* d_in, const int* in_sizes, int n_in,
                              void* d_out, int out_size, void* d_ws, size_t ws_size,
                              hipStream_t stream) {
    const float* x = (const float*)d_in[0];
    const float* adj = (const float*)d_in[1];
    const float* Wm = (const float*)d_in[2];
    const float* bias = (const float*)d_in[3];
    const float* attw = (const float*)d_in[4];
    const float* attb = (const float*)d_in[5];
    float* out = (float*)d_out;

    float* ws = (float*)d_ws;
    float* h = ws;                                   // N*D floats
    float4* rowmeta = (float4*)(h + (size_t)N * D);  // N float4
    int2* edge_g = (int2*)(rowmeta + N);             // N*CAP int2 (j, aval)

    hipLaunchKernelGGL(k_rows, dim3(N), dim3(256), 0, stream, x, Wm, bias,
                       attw, attb, adj, h, rowmeta, edge_g);
    hipLaunchKernelGGL(k_agg, dim3(N), dim3(256), 0, stream, h, rowmeta,
                       edge_g, out);
}